// Round 8
// baseline (224.076 us; speedup 1.0000x reference)
//
#include <hip/hip_runtime.h>
#include <hip/hip_bf16.h>
#include <math.h>

#define T_   2048
#define B_   2
#define E_   1024
#define H_   16
#define D_   64
#define NH_  32
#define M_   4096

typedef __attribute__((ext_vector_type(8))) short s8b;   // 8 bf16 (4 VGPRs)
typedef __attribute__((ext_vector_type(4))) float f4;    // 4 f32 acc

#define MFMA_B16(a,b,c) __builtin_amdgcn_mfma_f32_16x16x32_bf16(a,b,c,0,0,0)
#define LOG2E 1.44269504088896f

__device__ __forceinline__ unsigned short f2bu(float f) {
    union { __hip_bfloat16 h; unsigned short u; } cv;
    cv.h = __float2bfloat16(f);
    return cv.u;
}
// fast bf16: round-half-up truncation (positive finite values) — 2 VALU ops
__device__ __forceinline__ unsigned short f2bu_fast(float f) {
    return (unsigned short)((__float_as_uint(f) + 0x8000u) >> 16);
}
__device__ __forceinline__ float bu2f(unsigned short u) {
    union { __hip_bfloat16 h; unsigned short u; } cv; cv.u = u;
    return __bfloat162float(cv.h);
}
__device__ __forceinline__ unsigned int pk2(float a, float b) {
    return (unsigned int)f2bu(a) | ((unsigned int)f2bu(b) << 16);
}
// pack two f32 -> packed bf16 pair with round-half-up (cheap)
__device__ __forceinline__ unsigned int pk2_fast(float a, float b) {
    return ((__float_as_uint(a) + 0x8000u) >> 16) |
           ((__float_as_uint(b) + 0x8000u) & 0xFFFF0000u);
}
// raw v_exp_f32 — exp2f() without fast-math expands to a denorm-guard
// sequence (~12 extra VALU ops); attention scores never reach denormals.
__device__ __forceinline__ float fexp2(float x) {
    return __builtin_amdgcn_exp2f(x);
}
__device__ __forceinline__ float ld1d(const void* p, size_t idx, bool f32) {
    return f32 ? ((const float*)p)[idx] : bu2f(((const unsigned short*)p)[idx]);
}
// sum across the 4 quads (lane bits 4-5)
__device__ __forceinline__ float qsumq(float v) {
    v += __shfl_xor(v, 16); v += __shfl_xor(v, 32);
    return v;
}
// async global->LDS, 16 B per lane (GEMMs only — attn uses register prefetch
// because its per-tile barrier drains vmcnt(0) and exposes the DMA latency)
__device__ __forceinline__ void glds16(const unsigned short* g, unsigned short* l) {
    __builtin_amdgcn_global_load_lds(
        (const __attribute__((address_space(1))) unsigned int*)g,
        (__attribute__((address_space(3))) unsigned int*)l, 16, 0, 0);
}
// dtype detect, wave-local (identical result in every wave): sample 64 u16
// words of x; bf16 data -> ~all exponent fields sane; f32-as-u16 -> ~half.
__device__ __forceinline__ bool detect_f32(const unsigned short* q16) {
    int e = (q16[threadIdx.x & 63] >> 7) & 0xFF;
    bool sane = (e == 0) || (e >= 97 && e <= 157);
    unsigned long long m = __ballot(sane);
    return __popcll(m) < 56;   // true = f32 inputs
}

// ---------------------------------------------------------------------------
// One-pass f32->bf16 conversion of x, Wq..Wo, bq..bo into ws. Also publishes
// the dtype flag (block (0,0) of the x region) for the attn/out kernels.
// ---------------------------------------------------------------------------
__global__ __launch_bounds__(256) void cvt_bf16(
    const void* __restrict__ x,
    const void* __restrict__ Wq, const void* __restrict__ Wk,
    const void* __restrict__ Wv, const void* __restrict__ Wo,
    const void* __restrict__ bq, const void* __restrict__ bk,
    const void* __restrict__ bv, const void* __restrict__ bo,
    unsigned short* __restrict__ xw, unsigned short* __restrict__ Ww,
    unsigned short* __restrict__ bw, int* __restrict__ flag)
{
    const bool f32m = detect_f32((const unsigned short*)x);
    if (blockIdx.x == 0 && blockIdx.y == 0 && threadIdx.x == 0)
        *flag = f32m ? 1 : 0;
    const int y = blockIdx.y;
    const void* src; unsigned short* dst; int n;
    if (y == 0)      { src = x; dst = xw; n = M_ * E_; }
    else if (y <= 4) {
        src = (y == 1) ? Wq : (y == 2) ? Wk : (y == 3) ? Wv : Wo;
        dst = Ww + (size_t)(y - 1) * E_ * E_; n = E_ * E_;
    } else {
        src = (y == 5) ? bq : (y == 6) ? bk : (y == 7) ? bv : bo;
        dst = bw + (size_t)(y - 5) * E_; n = E_;
    }
    int i = (blockIdx.x * 256 + threadIdx.x) * 8;
    if (i >= n) return;
    if (f32m) {
        const float* s = (const float*)src + i;
        float4 f0 = *(const float4*)s, f1 = *(const float4*)(s + 4);
        union { unsigned int d[4]; s8b v; } u;
        u.d[0] = pk2(f0.x, f0.y); u.d[1] = pk2(f0.z, f0.w);
        u.d[2] = pk2(f1.x, f1.y); u.d[3] = pk2(f1.z, f1.w);
        *(s8b*)(dst + i) = u.v;
    } else {
        *(s8b*)(dst + i) = *(const s8b*)((const unsigned short*)src + i);
    }
}

// ---------------------------------------------------------------------------
// QKV projection, bf16 MFMA GEMM, XCD swizzle, glds staging (xor-swizzled),
// double-buffered single-barrier. p==2 (V) is written TRANSPOSED [N][D][T].
// ---------------------------------------------------------------------------
__global__ __launch_bounds__(256, 3) void qkv_gemm(
    const unsigned short* __restrict__ xw, const unsigned short* __restrict__ Ww,
    const unsigned short* __restrict__ bw,
    unsigned short* __restrict__ qo, unsigned short* __restrict__ ko,
    unsigned short* __restrict__ vo)
{
    const int bid = blockIdx.x;            // 768 blocks
    const int r_ = bid & 7, s_ = bid >> 3;
    const int g = r_ + 8 * (s_ >> 3);      // group in [0,96): (m,p)
    const int e0 = (s_ & 7) * 128;
    const int m0 = (g & 31) * 128;
    const int p  = g >> 5;
    const unsigned short* W    = Ww + (size_t)p * E_ * E_;
    const unsigned short* bias = bw + (size_t)p * E_;
    const float scale = (p == 0) ? 0.125f * LOG2E : 1.0f;

    const int tid = threadIdx.x, w = tid >> 6, lane = tid & 63;
    const int quad = lane >> 4, lc = lane & 15;
    const int wx = w & 1, wy = w >> 1;

    __shared__ unsigned short a_s[2][128 * 32];
    __shared__ unsigned short b_s[2][128 * 32];

    f4 acc[4][4];
    #pragma unroll
    for (int i = 0; i < 4; i++)
        #pragma unroll
        for (int j = 0; j < 4; j++) acc[i][j] = (f4){0.f, 0.f, 0.f, 0.f};

    const int gr = lane >> 2;
    const int gc = (lane & 3) ^ ((lane >> 2) & 3);
    const size_t aoff = (size_t)(m0 + w*32 + gr) * E_ + gc*8;
    const size_t boff = (size_t)(e0 + w*32 + gr) * E_ + gc*8;

    #pragma unroll
    for (int j = 0; j < 2; j++) {
        glds16(xw + aoff + (size_t)j*16*E_, &a_s[0][(w*128 + j*64) * 8]);
        glds16(W  + boff + (size_t)j*16*E_, &b_s[0][(w*128 + j*64) * 8]);
    }
    __syncthreads();

    const int fcA = quad ^ (lc & 3);
    for (int k0 = 0; k0 < E_; k0 += 32) {
        const int cur = (k0 >> 5) & 1;
        if (k0 + 32 < E_) {
            #pragma unroll
            for (int j = 0; j < 2; j++) {
                glds16(xw + aoff + (size_t)j*16*E_ + k0 + 32, &a_s[cur^1][(w*128 + j*64) * 8]);
                glds16(W  + boff + (size_t)j*16*E_ + k0 + 32, &b_s[cur^1][(w*128 + j*64) * 8]);
            }
        }
        s8b af[4], bfr[4];
        #pragma unroll
        for (int i = 0; i < 4; i++)
            af[i]  = *(const s8b*)&a_s[cur][((wy*64 + i*16 + lc)*4 + fcA) * 8];
        #pragma unroll
        for (int i = 0; i < 4; i++)
            bfr[i] = *(const s8b*)&b_s[cur][((wx*64 + i*16 + lc)*4 + fcA) * 8];
        #pragma unroll
        for (int ms = 0; ms < 4; ms++)
            #pragma unroll
            for (int ns = 0; ns < 4; ns++)
                acc[ms][ns] = MFMA_B16(af[ms], bfr[ns], acc[ms][ns]);
        __syncthreads();
    }

    float bias_v[4];
    #pragma unroll
    for (int ns = 0; ns < 4; ns++) bias_v[ns] = bu2f(bias[e0 + wx*64 + ns*16 + lc]);

    if (p < 2) {
        #pragma unroll
        for (int ms = 0; ms < 4; ms++)
            #pragma unroll
            for (int ns = 0; ns < 4; ns++)
                #pragma unroll
                for (int r2 = 0; r2 < 4; r2++) {
                    float val = (acc[ms][ns][r2] + bias_v[ns]) * scale;
                    float nb = __shfl_xor(val, 1);
                    if (!(lane & 1)) {
                        int m = m0 + wy*64 + ms*16 + quad*4 + r2;
                        int t = m >> 1, bb = m & 1;
                        int e = e0 + wx*64 + ns*16 + lc;
                        int h = e >> 6, d = e & 63;
                        unsigned short* dst = (p == 0) ? qo : ko;
                        *(unsigned int*)&dst[(((size_t)(bb*H_ + h) * T_ + t) << 6) + d] = pk2(val, nb);
                    }
                }
    } else {
        // V transposed: vo[nh][d][t]
        #pragma unroll
        for (int ms = 0; ms < 4; ms++) {
            int t0v = (m0 + wy*64 + ms*16 + quad*4) >> 1;
            #pragma unroll
            for (int ns = 0; ns < 4; ns++) {
                int e = e0 + wx*64 + ns*16 + lc;
                int h = e >> 6, d = e & 63;
                float v0 = acc[ms][ns][0] + bias_v[ns];
                float v1 = acc[ms][ns][1] + bias_v[ns];
                float v2 = acc[ms][ns][2] + bias_v[ns];
                float v3 = acc[ms][ns][3] + bias_v[ns];
                *(unsigned int*)&vo[((size_t)h        * 64 + d) * T_ + t0v] = pk2(v0, v2);
                *(unsigned int*)&vo[((size_t)(H_ + h) * 64 + d) * T_ + t0v] = pk2(v1, v3);
            }
        }
    }
}

// ---------------------------------------------------------------------------
// Flash attention with Shaw bias — R18: R17 (8-wave, 512-thr, 2 blocks/CU,
// occupancy 19.8->35.5%, dur 85->72us) + two stall-overlap levers:
//  (1) tile-order STAGGER: block starts its K-sweep at tile ((bid>>3)&1)*16
//      (same-XCD neighbors opposite phase). Math is order-invariant: all
//      accumulations are tile-position-dependent sums, visit order free.
//      Desynchronizes co-resident blocks' barrier cadences.
//  (2) s_setprio(1) around MFMA clusters (T5): with 4 phase-diverse
//      waves/SIMD the scheduler can now prefer MFMA-entering waves.
// ---------------------------------------------------------------------------
__global__ __launch_bounds__(512, 4) void attn_mfma(
    const unsigned short* __restrict__ q, const unsigned short* __restrict__ k,
    const unsigned short* __restrict__ v,
    const void* __restrict__ rk_t, const void* __restrict__ rv_t,
    unsigned short* __restrict__ aout, const int* __restrict__ flag)
{
    const bool f32m = (*flag != 0);
    const int bid = blockIdx.x;
    const int n = bid & 31, qt = bid >> 5;
    const int t0 = qt * 128;
    const int tid = threadIdx.x, w = tid >> 6, lane = tid & 63;
    const int quad = lane >> 4, lc = lane & 15;

    __shared__ unsigned short k_s[2][64 * 64];   // K[s][d] swizzled (buf0: rv^T later)
    __shared__ unsigned short v_s[2][64 * 64];   // V^T[d][s] swizzled
    __shared__ unsigned short p_s[8][16 * 72];   // per-wave P[t][s] / P_extra; rk staging
    __shared__ unsigned short qrk_s[128 * 36];   // qrk[t_local][r] bf16 (log2 dom.)
    __shared__ unsigned short diag16[128 * 33];  // e-values at |rel|<16, bf16
    __shared__ float st_L[128], st_R[128];

    const unsigned short* qn = q + ((size_t)n * T_ + t0) * D_;
    const unsigned short* kn = k + (size_t)n * T_ * D_;
    const unsigned short* vn = v + (size_t)n * D_ * T_;   // V^T [D][T]

    // Q fragments (B-operand for S^T): 16 rows per wave (t = w*16 + lc)
    s8b qa[2];
    #pragma unroll
    for (int kf = 0; kf < 2; kf++)
        qa[kf] = *(const s8b*)(qn + (size_t)(w*16 + lc) * D_ + kf*32 + quad*8);

    for (int i = tid; i < 128 * 33; i += 512) diag16[i] = 0;

    // stage rk (bf16, padded [48][72], rows>=33 zero) into p_s area
    unsigned int* rks = (unsigned int*)&p_s[0][0];
    for (int i = tid; i < 48 * 36; i += 512) {
        int r = i / 36, c2 = i % 36;
        unsigned int val = 0;
        if (r < 33 && c2 < 32)
            val = pk2(ld1d(rk_t, r*64 + 2*c2, f32m), ld1d(rk_t, r*64 + 2*c2 + 1, f32m));
        rks[i] = val;
    }
    __syncthreads();

    // qrk[t][r] = q[t] . rk[r] via MFMA (prologue-only); rows w*16..w*16+15
    for (int nt = 0; nt < 3; nt++) {
        s8b b0 = *(const s8b*)((const unsigned short*)rks + (nt*16 + lc)*72 + quad*8);
        s8b b1 = *(const s8b*)((const unsigned short*)rks + (nt*16 + lc)*72 + 32 + quad*8);
        f4 a = (f4){0.f, 0.f, 0.f, 0.f};
        a = MFMA_B16(qa[0], b0, a);
        a = MFMA_B16(qa[1], b1, a);
        #pragma unroll
        for (int r = 0; r < 4; r++) {
            float nb = __shfl_xor(a[r], 1);
            int col = nt*16 + lc;
            if (!(lane & 1) && col < 34)
                ((unsigned int*)qrk_s)[(w*16 + quad*4 + r)*18 + (col >> 1)] = pk2(a[r], nb);
        }
    }
    __syncthreads();   // rk staging (aliased with p_s) free after this

    // per-lane Shaw edge biases (t = w*16 + lc)
    const int t_l = w*16 + lc;
    const float qLn = bu2f(qrk_s[t_l*36 + 0]);
    const float qRn = bu2f(qrk_s[t_l*36 + 32]);
    float L_p = 0.f, R_p = 0.f;
    f4 O[4], lsN, lsL, lsR;
    lsN = (f4){0.f, 0.f, 0.f, 0.f};
    lsL = (f4){0.f, 0.f, 0.f, 0.f};
    lsR = (f4){0.f, 0.f, 0.f, 0.f};
    #pragma unroll
    for (int dt = 0; dt < 4; dt++) O[dt] = (f4){0.f, 0.f, 0.f, 0.f};
    const short ob = (short)0x3F80;   // bf16 1.0
    const s8b ones = { ob, ob, ob, ob, ob, ob, ob, ob };

    // staging mapping: 512 threads cover the 64x64 tile in ONE 16B/thread
    // round. row = w*8 + grr, source chunk xor-swizzled: phys = src ^ (row&7).
    const int grr = lane >> 3;
    const int gcc = (lane & 7) ^ grr;
    const size_t koff = (size_t)(w*8 + grr) * D_ + gcc*8;   // + (s0)*D_
    const size_t voff = (size_t)(w*8 + grr) * T_ + gcc*8;   // + s0

    // tile-order stagger: co-resident blocks start 16 tiles apart
    const int kts = ((bid >> 3) & 1) * 16;

    // first tile register prefetch + write buf 0
    s8b kr0 = *(const s8b*)(kn + koff + (size_t)(kts * 64) * D_);
    s8b vr0 = *(const s8b*)(vn + voff + kts * 64);
    *(s8b*)&k_s[0][(w*64 + lane) * 8] = kr0;
    *(s8b*)&v_s[0][(w*64 + lane) * 8] = vr0;
    __syncthreads();

    const int lc7 = lc & 7;
    for (int it = 0; it < 32; it++) {
        const int kt = (it + kts) & 31;
        const int s0 = kt * 64;
        const int cur = it & 1;
        if (it + 1 < 32) {   // issue next tile's global loads now
            const int s0n = ((it + 1 + kts) & 31) * 64;
            kr0 = *(const s8b*)(kn + koff + (size_t)s0n * D_);
            vr0 = *(const s8b*)(vn + voff + s0n);
        }

        const bool farL  = (s0 + 63 < t0 - 16);
        const bool farR  = (s0 > t0 + 143);
        const bool nearT = !farL && !farR;

        // K fragments (A-operand for S^T): K[s=st*16+lc][d]
        s8b ak[4][2];
        #pragma unroll
        for (int st = 0; st < 4; st++) {
            int row = st*16 + lc;
            ak[st][0] = *(const s8b*)&k_s[cur][(row*8 + (quad       ^ lc7)) * 8];
            ak[st][1] = *(const s8b*)&k_s[cur][(row*8 + ((4 + quad) ^ lc7)) * 8];
        }

        // S^T = K·Q^T (+ bias), exp2, pack b64 into P[t][s]
        #pragma unroll
        for (int st = 0; st < 4; st++) {
            f4 a;
            if (nearT) a = (f4){0.f, 0.f, 0.f, 0.f};
            else {
                float qb = farL ? qLn : qRn;
                a = (f4){qb, qb, qb, qb};
            }
            __builtin_amdgcn_s_setprio(1);
            a = MFMA_B16(ak[st][0], qa[0], a);
            a = MFMA_B16(ak[st][1], qa[1], a);
            __builtin_amdgcn_s_setprio(0);
            unsigned int lo, hi;
            if (nearT) {
                const int sb = s0 + st*16 + quad*4 - (t0 + t_l);
                unsigned short eb[4];
                #pragma unroll
                for (int r = 0; r < 4; r++) {
                    int rel = sb + r;
                    int rc = rel < -16 ? -16 : (rel > 16 ? 16 : rel);
                    float e = fexp2(a[r] + bu2f(qrk_s[t_l*36 + rc + 16]));
                    eb[r] = f2bu_fast(e);
                    if (rel <= -16)      L_p += e;
                    else if (rel >= 16)  R_p += e;
                    else                 diag16[t_l*33 + rel + 15] = eb[r];
                }
                lo = (unsigned int)eb[0] | ((unsigned int)eb[1] << 16);
                hi = (unsigned int)eb[2] | ((unsigned int)eb[3] << 16);
            } else {
                lo = pk2_fast(fexp2(a[0]), fexp2(a[1]));
                hi = pk2_fast(fexp2(a[2]), fexp2(a[3]));
            }
            *(uint2*)&p_s[w][lc*72 + st*16 + quad*4] = make_uint2(lo, hi);
        }

        // P fragments (B-operand): P[t=lc][s=quad*8+j]
        s8b pb[2];
        pb[0] = *(const s8b*)&p_s[w][lc*72 + quad*8];
        pb[1] = *(const s8b*)&p_s[w][lc*72 + 32 + quad*8];
        // column sums of P^T (= row sums of P) via ones-MFMA + PV cluster
        __builtin_amdgcn_s_setprio(1);
        if (nearT) {
            lsN = MFMA_B16(ones, pb[0], lsN);
            lsN = MFMA_B16(ones, pb[1], lsN);
        } else if (farL) {
            lsL = MFMA_B16(ones, pb[0], lsL);
            lsL = MFMA_B16(ones, pb[1], lsL);
        } else {
            lsR = MFMA_B16(ones, pb[0], lsR);
            lsR = MFMA_B16(ones, pb[1], lsR);
        }
        // O^T += V^T · P^T
        #pragma unroll
        for (int dt = 0; dt < 4; dt++) {
            int row = dt*16 + lc;
            s8b a0 = *(const s8b*)&v_s[cur][(row*8 + (quad       ^ lc7)) * 8];
            s8b a1 = *(const s8b*)&v_s[cur][(row*8 + ((4 + quad) ^ lc7)) * 8];
            O[dt] = MFMA_B16(a0, pb[0], O[dt]);
            O[dt] = MFMA_B16(a1, pb[1], O[dt]);
        }
        __builtin_amdgcn_s_setprio(0);

        if (it + 1 < 32) {   // write prefetched tile to the other buffer
            *(s8b*)&k_s[cur ^ 1][(w*64 + lane) * 8] = kr0;
            *(s8b*)&v_s[cur ^ 1][(w*64 + lane) * 8] = vr0;
        }
        __syncthreads();
    }

    // ---- epilogue: totals, relpos-V via rv^T·P_extra^T, normalize, store ----
    float l = lsN[0] + lsL[0] + lsR[0];
    float L = lsL[0] + qsumq(L_p);
    float R = lsR[0] + qsumq(R_p);
    const float linv = 1.f / l;
    if (quad == 0) { st_L[t_l] = L; st_R[t_l] = R; }
    // stage rv TRANSPOSED into k_s[0] with the SAME xor swizzle (r>=33 zero)
    {
        unsigned int* rvs = (unsigned int*)&k_s[0][0];
        for (int i = tid; i < 64 * 32; i += 512) {
            int d = i >> 5, dwL = i & 31;
            int r0 = dwL * 2, r1 = r0 + 1;
            float x0 = (r0 < 33) ? ld1d(rv_t, (size_t)r0 * 64 + d, f32m) : 0.f;
            float x1 = (r1 < 33) ? ld1d(rv_t, (size_t)r1 * 64 + d, f32m) : 0.f;
            int phys = d * 32 + ((dwL >> 2) ^ (d & 7)) * 4 + (dwL & 3);
            rvs[phys] = pk2(x0, x1);
        }
    }
    __syncthreads();
    // build P_extra[16][64] bf16 in own wave region (cols 33..63 = 0)
    for (int j = 0; j < 16; j++) {
        int c = lane;
        int row = w*16 + j;
        unsigned short pv;
        if (c == 0)        pv = f2bu(st_L[row]);
        else if (c == 32)  pv = f2bu(st_R[row]);
        else if (c < 32)   pv = diag16[row*33 + c - 1];
        else               pv = 0;
        p_s[w][j*72 + c] = pv;
    }
    // O^T += rv^T · P_extra^T
    s8b pe[2];
    pe[0] = *(const s8b*)&p_s[w][lc*72 + quad*8];
    pe[1] = *(const s8b*)&p_s[w][lc*72 + 32 + quad*8];
    #pragma unroll
    for (int dt = 0; dt < 4; dt++) {
        int row = dt*16 + lc;
        s8b a0 = *(const s8b*)&k_s[0][(row*8 + (quad       ^ lc7)) * 8];
        s8b a1 = *(const s8b*)&k_s[0][(row*8 + ((4 + quad) ^ lc7)) * 8];
        O[dt] = MFMA_B16(a0, pe[0], O[dt]);
        O[dt] = MFMA_B16(a1, pe[1], O[dt]);
    }
    // normalize + store bf16 [T][B][E] — packed 8B store, no shfl
    const int bb = n >> 4, h = n & 15;
    {
        int t_g = t0 + t_l;
        #pragma unroll
        for (int dt = 0; dt < 4; dt++) {
            float v0 = O[dt][0] * linv;
            float v1 = O[dt][1] * linv;
            float v2 = O[dt][2] * linv;
            float v3 = O[dt][3] * linv;
            int e = h*64 + dt*16 + quad*4;
            *(uint2*)&aout[((size_t)t_g * B_ + bb) * E_ + e] =
                make_uint2(pk2(v0, v1), pk2(v2, v3));
        }
    }
}

// ---------------------------------------------------------------------------
// Output projection, bf16 MFMA GEMM, XCD swizzle, glds staging, dbuf.
// ---------------------------------------------------------------------------
__global__ __launch_bounds__(256, 3) void out_gemm(
    const unsigned short* __restrict__ A,
    const unsigned short* __restrict__ Wob, const unsigned short* __restrict__ bob,
    void* __restrict__ out, const int* __restrict__ flag)
{
    const bool f32m = (*flag != 0);
    const int bid = blockIdx.x;            // 256 blocks
    const int r_ = bid & 7, s_ = bid >> 3;
    const int g = r_ + 8 * (s_ >> 3);
    const int m0 = g * 128;
    const int e0 = (s_ & 7) * 128;

    const int tid = threadIdx.x, w = tid >> 6, lane = tid & 63;
    const int quad = lane >> 4, lc = lane & 15;
    const int wx = w & 1, wy = w >> 1;

    __shared__ unsigned short a_s[2][128 * 32];
    __shared__ unsigned short b_s[2][128 * 32];

    f4 acc[4][4];
    #pragma unroll
    for (int i = 0; i < 4; i++)
        #pragma unroll
        for (int j = 0; j < 4; j++) acc[i][j] = (f4){0.f, 0.f, 0.f, 0.f};

    const int gr = lane >> 2;
    const int gc = (lane & 3) ^ ((lane >> 2) & 3);
    const size_t aoff = (size_t)(m0 + w*32 + gr) * E_ + gc*8;
    const size_t boff = (size_t)(e0 + w*32 + gr) * E_ + gc*8;

    #pragma unroll
    for (int j = 0; j < 2; j++) {
        glds16(A   + aoff + (size_t)j*16*E_, &a_s[0][(w*128 + j*64) * 8]);
        glds16(Wob + boff + (size_t)j*16*E_, &b_s[0][(w*128 + j*64) * 8]);
    }
    __syncthreads();

    const int fcA = quad ^ (lc & 3);
    for (int k0 = 0; k0 < E_; k0 += 32) {
        const int cur = (k0 >> 5) & 1;
        if (k0 + 32 < E_) {
            #pragma unroll
            for (int j = 0; j < 2; j++) {
                glds16(A   + aoff + (size_t)j*16*E_ + k0 + 32, &a_s[cur^1][(w*128 + j*64) * 8]);
                glds16(Wob + boff + (size_t)j*16*E_ + k0 + 32, &b_s[cur^1][(w*128 + j*64) * 8]);
            }
        }
        s8b af[4], bfr[4];
        #pragma unroll
        for (int i = 0; i < 4; i++)
            af[i]  = *(const s8b*)&a_s[cur][((wy*64 + i*16 + lc)*4 + fcA) * 8];
        #pragma unroll
        for (int i = 0; i < 4; i++)
            bfr[i] = *(const s8b*)&b_s[cur][((wx*64 + i*16 + lc)*4 + fcA) * 8];
        #pragma unroll
        for (int ms = 0; ms < 4; ms++)
            #pragma unroll
            for (int ns = 0; ns < 4; ns++)
                acc[ms][ns] = MFMA_B16(af[ms], bfr[ns], acc[ms][ns]);
        __syncthreads();
    }

    float bias_v[4];
    #pragma unroll
    for (int ns = 0; ns < 4; ns++) bias_v[ns] = bu2f(bob[e0 + wx*64 + ns*16 + lc]);

    #pragma unroll
    for (int ms = 0; ms < 4; ms++)
        #pragma unroll
        for (int ns = 0; ns < 4; ns++)
            #pragma unroll
            for (int r2 = 0; r2 < 4; r2++) {
                float val = acc[ms][ns][r2] + bias_v[ns];
                size_t m = m0 + wy*64 + ms*16 + quad*4 + r2;
                int e = e0 + wx*64 + ns*16 + lc;
                if (f32m) {
                    ((float*)out)[m * E_ + e] = val;
                } else {
                    float nb = __shfl_xor(val, 1);
                    if (!(lane & 1))
                        *(unsigned int*)&((unsigned short*)out)[m * E_ + e] = pk2(val, nb);
                }
            }
}

extern "C" void kernel_launch(void* const* d_in, const int* in_sizes, int n_in,
                              void* d_out, int out_size, void* d_ws, size_t ws_size,
                              hipStream_t stream) {
    const void* x  = d_in[0];
    const void* Wq = d_in[1];  const void* bq = d_in[2];
    const void* Wk = d_in[3];  const void* bk = d_in[4];
    const void* Wv = d_in[5];  const void* bv = d_in[6];
    const void* Wo = d_in[7];  const void* bo = d_in[8];
    const void* rk = d_in[9];  const void* rv = d_in[10];

    int* flag = (int*)d_ws;
    const size_t HTD = (size_t)NH_ * T_ * D_;        // 4,194,304 elems
    unsigned short* qw = (unsigned short*)((char*)d_ws + 256);
    unsigned short* kw = qw + HTD;
    unsigned short* vw = kw + HTD;                   // V^T [N][D][T] bf16
    unsigned short* aw = vw + HTD;                   // [4096][1024] bf16 pre-Wo
    unsigned short* xw = aw + (size_t)M_ * E_;       // x as bf16 (8 MB)
    unsigned short* Ww = xw + (size_t)M_ * E_;       // Wq,Wk,Wv,Wo bf16 (8 MB)
    unsigned short* bw = Ww + (size_t)4 * E_ * E_;   // bq,bk,bv,bo bf16 (8 KB)
    // ws use: ~48 MB

    cvt_bf16<<<dim3((M_*E_/8 + 255)/256, 9), 256, 0, stream>>>(
        x, Wq, Wk, Wv, Wo, bq, bk, bv, bo, xw, Ww, bw, flag);
    qkv_gemm<<<dim3(768), 256, 0, stream>>>(xw, Ww, bw, qw, kw, vw);
    attn_mfma<<<dim3(NH_ * (T_/128)), 512, 0, stream>>>(qw, kw, vw, rk, rv, aw, flag);
    out_gemm<<<dim3(256), 256, 0, stream>>>(aw, Ww + (size_t)3*E_*E_, bw + 3*E_,
                                            d_out, flag);
}

// Round 9
// 220.755 us; speedup vs baseline: 1.0150x; 1.0150x over previous
//
#include <hip/hip_runtime.h>
#include <hip/hip_bf16.h>
#include <math.h>

#define T_   2048
#define B_   2
#define E_   1024
#define H_   16
#define D_   64
#define NH_  32
#define M_   4096

typedef __attribute__((ext_vector_type(8))) short s8b;   // 8 bf16 (4 VGPRs)
typedef __attribute__((ext_vector_type(4))) float f4;    // 4 f32 acc

#define MFMA_B16(a,b,c) __builtin_amdgcn_mfma_f32_16x16x32_bf16(a,b,c,0,0,0)
#define LOG2E 1.44269504088896f

__device__ __forceinline__ unsigned short f2bu(float f) {
    union { __hip_bfloat16 h; unsigned short u; } cv;
    cv.h = __float2bfloat16(f);
    return cv.u;
}
// fast bf16: round-half-up truncation (positive finite values) — 2 VALU ops
__device__ __forceinline__ unsigned short f2bu_fast(float f) {
    return (unsigned short)((__float_as_uint(f) + 0x8000u) >> 16);
}
__device__ __forceinline__ float bu2f(unsigned short u) {
    union { __hip_bfloat16 h; unsigned short u; } cv; cv.u = u;
    return __bfloat162float(cv.h);
}
__device__ __forceinline__ unsigned int pk2(float a, float b) {
    return (unsigned int)f2bu(a) | ((unsigned int)f2bu(b) << 16);
}
// pack two f32 -> packed bf16 pair with round-half-up (cheap)
__device__ __forceinline__ unsigned int pk2_fast(float a, float b) {
    return ((__float_as_uint(a) + 0x8000u) >> 16) |
           ((__float_as_uint(b) + 0x8000u) & 0xFFFF0000u);
}
// raw v_exp_f32 — exp2f() without fast-math expands to a denorm-guard
// sequence (~12 extra VALU ops); attention scores never reach denormals.
__device__ __forceinline__ float fexp2(float x) {
    return __builtin_amdgcn_exp2f(x);
}
__device__ __forceinline__ float ld1d(const void* p, size_t idx, bool f32) {
    return f32 ? ((const float*)p)[idx] : bu2f(((const unsigned short*)p)[idx]);
}
// sum across the 4 quads (lane bits 4-5)
__device__ __forceinline__ float qsumq(float v) {
    v += __shfl_xor(v, 16); v += __shfl_xor(v, 32);
    return v;
}
// async global->LDS, 16 B per lane (GEMMs only — attn uses register prefetch
// because its per-tile barrier drains vmcnt(0) and exposes the DMA latency)
__device__ __forceinline__ void glds16(const unsigned short* g, unsigned short* l) {
    __builtin_amdgcn_global_load_lds(
        (const __attribute__((address_space(1))) unsigned int*)g,
        (__attribute__((address_space(3))) unsigned int*)l, 16, 0, 0);
}
// dtype detect, wave-local (identical result in every wave): sample 64 u16
// words of x; bf16 data -> ~all exponent fields sane; f32-as-u16 -> ~half.
__device__ __forceinline__ bool detect_f32(const unsigned short* q16) {
    int e = (q16[threadIdx.x & 63] >> 7) & 0xFF;
    bool sane = (e == 0) || (e >= 97 && e <= 157);
    unsigned long long m = __ballot(sane);
    return __popcll(m) < 56;   // true = f32 inputs
}

// ---------------------------------------------------------------------------
// One-pass f32->bf16 conversion of x, Wq..Wo, bq..bo into ws. Also publishes
// the dtype flag (block (0,0) of the x region) for the attn/out kernels.
// ---------------------------------------------------------------------------
__global__ __launch_bounds__(256) void cvt_bf16(
    const void* __restrict__ x,
    const void* __restrict__ Wq, const void* __restrict__ Wk,
    const void* __restrict__ Wv, const void* __restrict__ Wo,
    const void* __restrict__ bq, const void* __restrict__ bk,
    const void* __restrict__ bv, const void* __restrict__ bo,
    unsigned short* __restrict__ xw, unsigned short* __restrict__ Ww,
    unsigned short* __restrict__ bw, int* __restrict__ flag)
{
    const bool f32m = detect_f32((const unsigned short*)x);
    if (blockIdx.x == 0 && blockIdx.y == 0 && threadIdx.x == 0)
        *flag = f32m ? 1 : 0;
    const int y = blockIdx.y;
    const void* src; unsigned short* dst; int n;
    if (y == 0)      { src = x; dst = xw; n = M_ * E_; }
    else if (y <= 4) {
        src = (y == 1) ? Wq : (y == 2) ? Wk : (y == 3) ? Wv : Wo;
        dst = Ww + (size_t)(y - 1) * E_ * E_; n = E_ * E_;
    } else {
        src = (y == 5) ? bq : (y == 6) ? bk : (y == 7) ? bv : bo;
        dst = bw + (size_t)(y - 5) * E_; n = E_;
    }
    int i = (blockIdx.x * 256 + threadIdx.x) * 8;
    if (i >= n) return;
    if (f32m) {
        const float* s = (const float*)src + i;
        float4 f0 = *(const float4*)s, f1 = *(const float4*)(s + 4);
        union { unsigned int d[4]; s8b v; } u;
        u.d[0] = pk2(f0.x, f0.y); u.d[1] = pk2(f0.z, f0.w);
        u.d[2] = pk2(f1.x, f1.y); u.d[3] = pk2(f1.z, f1.w);
        *(s8b*)(dst + i) = u.v;
    } else {
        *(s8b*)(dst + i) = *(const s8b*)((const unsigned short*)src + i);
    }
}

// ---------------------------------------------------------------------------
// QKV projection, bf16 MFMA GEMM, XCD swizzle, glds staging (xor-swizzled),
// double-buffered single-barrier. p==2 (V) is written TRANSPOSED [N][D][T].
// ---------------------------------------------------------------------------
__global__ __launch_bounds__(256, 3) void qkv_gemm(
    const unsigned short* __restrict__ xw, const unsigned short* __restrict__ Ww,
    const unsigned short* __restrict__ bw,
    unsigned short* __restrict__ qo, unsigned short* __restrict__ ko,
    unsigned short* __restrict__ vo)
{
    const int bid = blockIdx.x;            // 768 blocks
    const int r_ = bid & 7, s_ = bid >> 3;
    const int g = r_ + 8 * (s_ >> 3);      // group in [0,96): (m,p)
    const int e0 = (s_ & 7) * 128;
    const int m0 = (g & 31) * 128;
    const int p  = g >> 5;
    const unsigned short* W    = Ww + (size_t)p * E_ * E_;
    const unsigned short* bias = bw + (size_t)p * E_;
    const float scale = (p == 0) ? 0.125f * LOG2E : 1.0f;

    const int tid = threadIdx.x, w = tid >> 6, lane = tid & 63;
    const int quad = lane >> 4, lc = lane & 15;
    const int wx = w & 1, wy = w >> 1;

    __shared__ unsigned short a_s[2][128 * 32];
    __shared__ unsigned short b_s[2][128 * 32];

    f4 acc[4][4];
    #pragma unroll
    for (int i = 0; i < 4; i++)
        #pragma unroll
        for (int j = 0; j < 4; j++) acc[i][j] = (f4){0.f, 0.f, 0.f, 0.f};

    const int gr = lane >> 2;
    const int gc = (lane & 3) ^ ((lane >> 2) & 3);
    const size_t aoff = (size_t)(m0 + w*32 + gr) * E_ + gc*8;
    const size_t boff = (size_t)(e0 + w*32 + gr) * E_ + gc*8;

    #pragma unroll
    for (int j = 0; j < 2; j++) {
        glds16(xw + aoff + (size_t)j*16*E_, &a_s[0][(w*128 + j*64) * 8]);
        glds16(W  + boff + (size_t)j*16*E_, &b_s[0][(w*128 + j*64) * 8]);
    }
    __syncthreads();

    const int fcA = quad ^ (lc & 3);
    for (int k0 = 0; k0 < E_; k0 += 32) {
        const int cur = (k0 >> 5) & 1;
        if (k0 + 32 < E_) {
            #pragma unroll
            for (int j = 0; j < 2; j++) {
                glds16(xw + aoff + (size_t)j*16*E_ + k0 + 32, &a_s[cur^1][(w*128 + j*64) * 8]);
                glds16(W  + boff + (size_t)j*16*E_ + k0 + 32, &b_s[cur^1][(w*128 + j*64) * 8]);
            }
        }
        s8b af[4], bfr[4];
        #pragma unroll
        for (int i = 0; i < 4; i++)
            af[i]  = *(const s8b*)&a_s[cur][((wy*64 + i*16 + lc)*4 + fcA) * 8];
        #pragma unroll
        for (int i = 0; i < 4; i++)
            bfr[i] = *(const s8b*)&b_s[cur][((wx*64 + i*16 + lc)*4 + fcA) * 8];
        #pragma unroll
        for (int ms = 0; ms < 4; ms++)
            #pragma unroll
            for (int ns = 0; ns < 4; ns++)
                acc[ms][ns] = MFMA_B16(af[ms], bfr[ns], acc[ms][ns]);
        __syncthreads();
    }

    float bias_v[4];
    #pragma unroll
    for (int ns = 0; ns < 4; ns++) bias_v[ns] = bu2f(bias[e0 + wx*64 + ns*16 + lc]);

    if (p < 2) {
        #pragma unroll
        for (int ms = 0; ms < 4; ms++)
            #pragma unroll
            for (int ns = 0; ns < 4; ns++)
                #pragma unroll
                for (int r2 = 0; r2 < 4; r2++) {
                    float val = (acc[ms][ns][r2] + bias_v[ns]) * scale;
                    float nb = __shfl_xor(val, 1);
                    if (!(lane & 1)) {
                        int m = m0 + wy*64 + ms*16 + quad*4 + r2;
                        int t = m >> 1, bb = m & 1;
                        int e = e0 + wx*64 + ns*16 + lc;
                        int h = e >> 6, d = e & 63;
                        unsigned short* dst = (p == 0) ? qo : ko;
                        *(unsigned int*)&dst[(((size_t)(bb*H_ + h) * T_ + t) << 6) + d] = pk2(val, nb);
                    }
                }
    } else {
        // V transposed: vo[nh][d][t]
        #pragma unroll
        for (int ms = 0; ms < 4; ms++) {
            int t0v = (m0 + wy*64 + ms*16 + quad*4) >> 1;
            #pragma unroll
            for (int ns = 0; ns < 4; ns++) {
                int e = e0 + wx*64 + ns*16 + lc;
                int h = e >> 6, d = e & 63;
                float v0 = acc[ms][ns][0] + bias_v[ns];
                float v1 = acc[ms][ns][1] + bias_v[ns];
                float v2 = acc[ms][ns][2] + bias_v[ns];
                float v3 = acc[ms][ns][3] + bias_v[ns];
                *(unsigned int*)&vo[((size_t)h        * 64 + d) * T_ + t0v] = pk2(v0, v2);
                *(unsigned int*)&vo[((size_t)(H_ + h) * 64 + d) * T_ + t0v] = pk2(v1, v3);
            }
        }
    }
}

// ---------------------------------------------------------------------------
// Flash attention with Shaw bias — R19: R17 (8-wave, 512-thr, 72.0us) +
// CORRECTED tile-order stagger. R18's stagger bit (bid>>3)&1 was a no-op
// for co-resident pairs: with 512 blocks round-robined over 8 XCDs x 32
// CUs, the pair sharing a CU is (bid, bid+256), and ((bid+256)>>3)&1 ==
// (bid>>3)&1. Correct bit: (bid>>8)&1 — blocks 0-255 start the K-sweep at
// tile 0, blocks 256-511 at tile 16 — so the two co-resident blocks run
// opposite barrier/memory phases. setprio REVERTED (R18 isolated it as
// mildly negative: per-tile barrier lockstep makes this kernel GEMM-like
// for T5's mechanism, cf. m190). Math is order-invariant over kt.
// ---------------------------------------------------------------------------
__global__ __launch_bounds__(512, 4) void attn_mfma(
    const unsigned short* __restrict__ q, const unsigned short* __restrict__ k,
    const unsigned short* __restrict__ v,
    const void* __restrict__ rk_t, const void* __restrict__ rv_t,
    unsigned short* __restrict__ aout, const int* __restrict__ flag)
{
    const bool f32m = (*flag != 0);
    const int bid = blockIdx.x;
    const int n = bid & 31, qt = bid >> 5;
    const int t0 = qt * 128;
    const int tid = threadIdx.x, w = tid >> 6, lane = tid & 63;
    const int quad = lane >> 4, lc = lane & 15;

    __shared__ unsigned short k_s[2][64 * 64];   // K[s][d] swizzled (buf0: rv^T later)
    __shared__ unsigned short v_s[2][64 * 64];   // V^T[d][s] swizzled
    __shared__ unsigned short p_s[8][16 * 72];   // per-wave P[t][s] / P_extra; rk staging
    __shared__ unsigned short qrk_s[128 * 36];   // qrk[t_local][r] bf16 (log2 dom.)
    __shared__ unsigned short diag16[128 * 33];  // e-values at |rel|<16, bf16
    __shared__ float st_L[128], st_R[128];

    const unsigned short* qn = q + ((size_t)n * T_ + t0) * D_;
    const unsigned short* kn = k + (size_t)n * T_ * D_;
    const unsigned short* vn = v + (size_t)n * D_ * T_;   // V^T [D][T]

    // Q fragments (B-operand for S^T): 16 rows per wave (t = w*16 + lc)
    s8b qa[2];
    #pragma unroll
    for (int kf = 0; kf < 2; kf++)
        qa[kf] = *(const s8b*)(qn + (size_t)(w*16 + lc) * D_ + kf*32 + quad*8);

    for (int i = tid; i < 128 * 33; i += 512) diag16[i] = 0;

    // stage rk (bf16, padded [48][72], rows>=33 zero) into p_s area
    unsigned int* rks = (unsigned int*)&p_s[0][0];
    for (int i = tid; i < 48 * 36; i += 512) {
        int r = i / 36, c2 = i % 36;
        unsigned int val = 0;
        if (r < 33 && c2 < 32)
            val = pk2(ld1d(rk_t, r*64 + 2*c2, f32m), ld1d(rk_t, r*64 + 2*c2 + 1, f32m));
        rks[i] = val;
    }
    __syncthreads();

    // qrk[t][r] = q[t] . rk[r] via MFMA (prologue-only); rows w*16..w*16+15
    for (int nt = 0; nt < 3; nt++) {
        s8b b0 = *(const s8b*)((const unsigned short*)rks + (nt*16 + lc)*72 + quad*8);
        s8b b1 = *(const s8b*)((const unsigned short*)rks + (nt*16 + lc)*72 + 32 + quad*8);
        f4 a = (f4){0.f, 0.f, 0.f, 0.f};
        a = MFMA_B16(qa[0], b0, a);
        a = MFMA_B16(qa[1], b1, a);
        #pragma unroll
        for (int r = 0; r < 4; r++) {
            float nb = __shfl_xor(a[r], 1);
            int col = nt*16 + lc;
            if (!(lane & 1) && col < 34)
                ((unsigned int*)qrk_s)[(w*16 + quad*4 + r)*18 + (col >> 1)] = pk2(a[r], nb);
        }
    }
    __syncthreads();   // rk staging (aliased with p_s) free after this

    // per-lane Shaw edge biases (t = w*16 + lc)
    const int t_l = w*16 + lc;
    const float qLn = bu2f(qrk_s[t_l*36 + 0]);
    const float qRn = bu2f(qrk_s[t_l*36 + 32]);
    float L_p = 0.f, R_p = 0.f;
    f4 O[4], lsN, lsL, lsR;
    lsN = (f4){0.f, 0.f, 0.f, 0.f};
    lsL = (f4){0.f, 0.f, 0.f, 0.f};
    lsR = (f4){0.f, 0.f, 0.f, 0.f};
    #pragma unroll
    for (int dt = 0; dt < 4; dt++) O[dt] = (f4){0.f, 0.f, 0.f, 0.f};
    const short ob = (short)0x3F80;   // bf16 1.0
    const s8b ones = { ob, ob, ob, ob, ob, ob, ob, ob };

    // staging mapping: 512 threads cover the 64x64 tile in ONE 16B/thread
    // round. row = w*8 + grr, source chunk xor-swizzled: phys = src ^ (row&7).
    const int grr = lane >> 3;
    const int gcc = (lane & 7) ^ grr;
    const size_t koff = (size_t)(w*8 + grr) * D_ + gcc*8;   // + (s0)*D_
    const size_t voff = (size_t)(w*8 + grr) * T_ + gcc*8;   // + s0

    // tile-order stagger: co-resident pair (bid, bid+256) -> opposite phase
    const int kts = ((bid >> 8) & 1) * 16;

    // first tile register prefetch + write buf 0
    s8b kr0 = *(const s8b*)(kn + koff + (size_t)(kts * 64) * D_);
    s8b vr0 = *(const s8b*)(vn + voff + kts * 64);
    *(s8b*)&k_s[0][(w*64 + lane) * 8] = kr0;
    *(s8b*)&v_s[0][(w*64 + lane) * 8] = vr0;
    __syncthreads();

    const int lc7 = lc & 7;
    for (int it = 0; it < 32; it++) {
        const int kt = (it + kts) & 31;
        const int s0 = kt * 64;
        const int cur = it & 1;
        if (it + 1 < 32) {   // issue next tile's global loads now
            const int s0n = ((it + 1 + kts) & 31) * 64;
            kr0 = *(const s8b*)(kn + koff + (size_t)s0n * D_);
            vr0 = *(const s8b*)(vn + voff + s0n);
        }

        const bool farL  = (s0 + 63 < t0 - 16);
        const bool farR  = (s0 > t0 + 143);
        const bool nearT = !farL && !farR;

        // K fragments (A-operand for S^T): K[s=st*16+lc][d]
        s8b ak[4][2];
        #pragma unroll
        for (int st = 0; st < 4; st++) {
            int row = st*16 + lc;
            ak[st][0] = *(const s8b*)&k_s[cur][(row*8 + (quad       ^ lc7)) * 8];
            ak[st][1] = *(const s8b*)&k_s[cur][(row*8 + ((4 + quad) ^ lc7)) * 8];
        }

        // S^T = K·Q^T (+ bias), exp2, pack b64 into P[t][s]
        #pragma unroll
        for (int st = 0; st < 4; st++) {
            f4 a;
            if (nearT) a = (f4){0.f, 0.f, 0.f, 0.f};
            else {
                float qb = farL ? qLn : qRn;
                a = (f4){qb, qb, qb, qb};
            }
            a = MFMA_B16(ak[st][0], qa[0], a);
            a = MFMA_B16(ak[st][1], qa[1], a);
            unsigned int lo, hi;
            if (nearT) {
                const int sb = s0 + st*16 + quad*4 - (t0 + t_l);
                unsigned short eb[4];
                #pragma unroll
                for (int r = 0; r < 4; r++) {
                    int rel = sb + r;
                    int rc = rel < -16 ? -16 : (rel > 16 ? 16 : rel);
                    float e = fexp2(a[r] + bu2f(qrk_s[t_l*36 + rc + 16]));
                    eb[r] = f2bu_fast(e);
                    if (rel <= -16)      L_p += e;
                    else if (rel >= 16)  R_p += e;
                    else                 diag16[t_l*33 + rel + 15] = eb[r];
                }
                lo = (unsigned int)eb[0] | ((unsigned int)eb[1] << 16);
                hi = (unsigned int)eb[2] | ((unsigned int)eb[3] << 16);
            } else {
                lo = pk2_fast(fexp2(a[0]), fexp2(a[1]));
                hi = pk2_fast(fexp2(a[2]), fexp2(a[3]));
            }
            *(uint2*)&p_s[w][lc*72 + st*16 + quad*4] = make_uint2(lo, hi);
        }

        // P fragments (B-operand): P[t=lc][s=quad*8+j]
        s8b pb[2];
        pb[0] = *(const s8b*)&p_s[w][lc*72 + quad*8];
        pb[1] = *(const s8b*)&p_s[w][lc*72 + 32 + quad*8];
        // column sums of P^T (= row sums of P) via ones-MFMA
        if (nearT) {
            lsN = MFMA_B16(ones, pb[0], lsN);
            lsN = MFMA_B16(ones, pb[1], lsN);
        } else if (farL) {
            lsL = MFMA_B16(ones, pb[0], lsL);
            lsL = MFMA_B16(ones, pb[1], lsL);
        } else {
            lsR = MFMA_B16(ones, pb[0], lsR);
            lsR = MFMA_B16(ones, pb[1], lsR);
        }
        // O^T += V^T · P^T
        #pragma unroll
        for (int dt = 0; dt < 4; dt++) {
            int row = dt*16 + lc;
            s8b a0 = *(const s8b*)&v_s[cur][(row*8 + (quad       ^ lc7)) * 8];
            s8b a1 = *(const s8b*)&v_s[cur][(row*8 + ((4 + quad) ^ lc7)) * 8];
            O[dt] = MFMA_B16(a0, pb[0], O[dt]);
            O[dt] = MFMA_B16(a1, pb[1], O[dt]);
        }

        if (it + 1 < 32) {   // write prefetched tile to the other buffer
            *(s8b*)&k_s[cur ^ 1][(w*64 + lane) * 8] = kr0;
            *(s8b*)&v_s[cur ^ 1][(w*64 + lane) * 8] = vr0;
        }
        __syncthreads();
    }

    // ---- epilogue: totals, relpos-V via rv^T·P_extra^T, normalize, store ----
    float l = lsN[0] + lsL[0] + lsR[0];
    float L = lsL[0] + qsumq(L_p);
    float R = lsR[0] + qsumq(R_p);
    const float linv = 1.f / l;
    if (quad == 0) { st_L[t_l] = L; st_R[t_l] = R; }
    // stage rv TRANSPOSED into k_s[0] with the SAME xor swizzle (r>=33 zero)
    {
        unsigned int* rvs = (unsigned int*)&k_s[0][0];
        for (int i = tid; i < 64 * 32; i += 512) {
            int d = i >> 5, dwL = i & 31;
            int r0 = dwL * 2, r1 = r0 + 1;
            float x0 = (r0 < 33) ? ld1d(rv_t, (size_t)r0 * 64 + d, f32m) : 0.f;
            float x1 = (r1 < 33) ? ld1d(rv_t, (size_t)r1 * 64 + d, f32m) : 0.f;
            int phys = d * 32 + ((dwL >> 2) ^ (d & 7)) * 4 + (dwL & 3);
            rvs[phys] = pk2(x0, x1);
        }
    }
    __syncthreads();
    // build P_extra[16][64] bf16 in own wave region (cols 33..63 = 0)
    for (int j = 0; j < 16; j++) {
        int c = lane;
        int row = w*16 + j;
        unsigned short pv;
        if (c == 0)        pv = f2bu(st_L[row]);
        else if (c == 32)  pv = f2bu(st_R[row]);
        else if (c < 32)   pv = diag16[row*33 + c - 1];
        else               pv = 0;
        p_s[w][j*72 + c] = pv;
    }
    // O^T += rv^T · P_extra^T
    s8b pe[2];
    pe[0] = *(const s8b*)&p_s[w][lc*72 + quad*8];
    pe[1] = *(const s8b*)&p_s[w][lc*72 + 32 + quad*8];
    #pragma unroll
    for (int dt = 0; dt < 4; dt++) {
        int row = dt*16 + lc;
        s8b a0 = *(const s8b*)&k_s[0][(row*8 + (quad       ^ lc7)) * 8];
        s8b a1 = *(const s8b*)&k_s[0][(row*8 + ((4 + quad) ^ lc7)) * 8];
        O[dt] = MFMA_B16(a0, pe[0], O[dt]);
        O[dt] = MFMA_B16(a1, pe[1], O[dt]);
    }
    // normalize + store bf16 [T][B][E] — packed 8B store, no shfl
    const int bb = n >> 4, h = n & 15;
    {
        int t_g = t0 + t_l;
        #pragma unroll
        for (int dt = 0; dt < 4; dt++) {
            float v0 = O[dt][0] * linv;
            float v1 = O[dt][1] * linv;
            float v2 = O[dt][2] * linv;
            float v3 = O[dt][3] * linv;
            int e = h*64 + dt*16 + quad*4;
            *(uint2*)&aout[((size_t)t_g * B_ + bb) * E_ + e] =
                make_uint2(pk2(v0, v1), pk2(v2, v3));
        }
    }
}

// ---------------------------------------------------------------------------
// Output projection, bf16 MFMA GEMM, XCD swizzle, glds staging, dbuf.
// ---------------------------------------------------------------------------
__global__ __launch_bounds__(256, 3) void out_gemm(
    const unsigned short* __restrict__ A,
    const unsigned short* __restrict__ Wob, const unsigned short* __restrict__ bob,
    void* __restrict__ out, const int* __restrict__ flag)
{
    const bool f32m = (*flag != 0);
    const int bid = blockIdx.x;            // 256 blocks
    const int r_ = bid & 7, s_ = bid >> 3;
    const int g = r_ + 8 * (s_ >> 3);
    const int m0 = g * 128;
    const int e0 = (s_ & 7) * 128;

    const int tid = threadIdx.x, w = tid >> 6, lane = tid & 63;
    const int quad = lane >> 4, lc = lane & 15;
    const int wx = w & 1, wy = w >> 1;

    __shared__ unsigned short a_s[2][128 * 32];
    __shared__ unsigned short b_s[2][128 * 32];

    f4 acc[4][4];
    #pragma unroll
    for (int i = 0; i < 4; i++)
        #pragma unroll
        for (int j = 0; j < 4; j++) acc[i][j] = (f4){0.f, 0.f, 0.f, 0.f};

    const int gr = lane >> 2;
    const int gc = (lane & 3) ^ ((lane >> 2) & 3);
    const size_t aoff = (size_t)(m0 + w*32 + gr) * E_ + gc*8;
    const size_t boff = (size_t)(e0 + w*32 + gr) * E_ + gc*8;

    #pragma unroll
    for (int j = 0; j < 2; j++) {
        glds16(A   + aoff + (size_t)j*16*E_, &a_s[0][(w*128 + j*64) * 8]);
        glds16(Wob + boff + (size_t)j*16*E_, &b_s[0][(w*128 + j*64) * 8]);
    }
    __syncthreads();

    const int fcA = quad ^ (lc & 3);
    for (int k0 = 0; k0 < E_; k0 += 32) {
        const int cur = (k0 >> 5) & 1;
        if (k0 + 32 < E_) {
            #pragma unroll
            for (int j = 0; j < 2; j++) {
                glds16(A   + aoff + (size_t)j*16*E_ + k0 + 32, &a_s[cur^1][(w*128 + j*64) * 8]);
                glds16(Wob + boff + (size_t)j*16*E_ + k0 + 32, &b_s[cur^1][(w*128 + j*64) * 8]);
            }
        }
        s8b af[4], bfr[4];
        #pragma unroll
        for (int i = 0; i < 4; i++)
            af[i]  = *(const s8b*)&a_s[cur][((wy*64 + i*16 + lc)*4 + fcA) * 8];
        #pragma unroll
        for (int i = 0; i < 4; i++)
            bfr[i] = *(const s8b*)&b_s[cur][((wx*64 + i*16 + lc)*4 + fcA) * 8];
        #pragma unroll
        for (int ms = 0; ms < 4; ms++)
            #pragma unroll
            for (int ns = 0; ns < 4; ns++)
                acc[ms][ns] = MFMA_B16(af[ms], bfr[ns], acc[ms][ns]);
        __syncthreads();
    }

    float bias_v[4];
    #pragma unroll
    for (int ns = 0; ns < 4; ns++) bias_v[ns] = bu2f(bob[e0 + wx*64 + ns*16 + lc]);

    #pragma unroll
    for (int ms = 0; ms < 4; ms++)
        #pragma unroll
        for (int ns = 0; ns < 4; ns++)
            #pragma unroll
            for (int r2 = 0; r2 < 4; r2++) {
                float val = acc[ms][ns][r2] + bias_v[ns];
                size_t m = m0 + wy*64 + ms*16 + quad*4 + r2;
                int e = e0 + wx*64 + ns*16 + lc;
                if (f32m) {
                    ((float*)out)[m * E_ + e] = val;
                } else {
                    float nb = __shfl_xor(val, 1);
                    if (!(lane & 1))
                        *(unsigned int*)&((unsigned short*)out)[m * E_ + e] = pk2(val, nb);
                }
            }
}

extern "C" void kernel_launch(void* const* d_in, const int* in_sizes, int n_in,
                              void* d_out, int out_size, void* d_ws, size_t ws_size,
                              hipStream_t stream) {
    const void* x  = d_in[0];
    const void* Wq = d_in[1];  const void* bq = d_in[2];
    const void* Wk = d_in[3];  const void* bk = d_in[4];
    const void* Wv = d_in[5];  const void* bv = d_in[6];
    const void* Wo = d_in[7];  const void* bo = d_in[8];
    const void* rk = d_in[9];  const void* rv = d_in[10];

    int* flag = (int*)d_ws;
    const size_t HTD = (size_t)NH_ * T_ * D_;        // 4,194,304 elems
    unsigned short* qw = (unsigned short*)((char*)d_ws + 256);
    unsigned short* kw = qw + HTD;
    unsigned short* vw = kw + HTD;                   // V^T [N][D][T] bf16
    unsigned short* aw = vw + HTD;                   // [4096][1024] bf16 pre-Wo
    unsigned short* xw = aw + (size_t)M_ * E_;       // x as bf16 (8 MB)
    unsigned short* Ww = xw + (size_t)M_ * E_;       // Wq,Wk,Wv,Wo bf16 (8 MB)
    unsigned short* bw = Ww + (size_t)4 * E_ * E_;   // bq,bk,bv,bo bf16 (8 KB)
    // ws use: ~48 MB

    cvt_bf16<<<dim3((M_*E_/8 + 255)/256, 9), 256, 0, stream>>>(
        x, Wq, Wk, Wv, Wo, bq, bk, bv, bo, xw, Ww, bw, flag);
    qkv_gemm<<<dim3(768), 256, 0, stream>>>(xw, Ww, bw, qw, kw, vw);
    attn_mfma<<<dim3(NH_ * (T_/128)), 512, 0, stream>>>(qw, kw, vw, rk, rv, aw, flag);
    out_gemm<<<dim3(256), 256, 0, stream>>>(aw, Ww + (size_t)3*E_*E_, bw + 3*E_,
                                            d_out, flag);
}

// Round 10
// 216.529 us; speedup vs baseline: 1.0349x; 1.0195x over previous
//
#include <hip/hip_runtime.h>
#include <hip/hip_bf16.h>
#include <math.h>

#define T_   2048
#define B_   2
#define E_   1024
#define H_   16
#define D_   64
#define NH_  32
#define M_   4096

typedef __attribute__((ext_vector_type(8))) short s8b;   // 8 bf16 (4 VGPRs)
typedef __attribute__((ext_vector_type(4))) float f4;    // 4 f32 acc

#define MFMA_B16(a,b,c) __builtin_amdgcn_mfma_f32_16x16x32_bf16(a,b,c,0,0,0)
#define LOG2E 1.44269504088896f

__device__ __forceinline__ unsigned short f2bu(float f) {
    union { __hip_bfloat16 h; unsigned short u; } cv;
    cv.h = __float2bfloat16(f);
    return cv.u;
}
// fast bf16: round-half-up truncation (positive finite values) — 2 VALU ops
__device__ __forceinline__ unsigned short f2bu_fast(float f) {
    return (unsigned short)((__float_as_uint(f) + 0x8000u) >> 16);
}
__device__ __forceinline__ float bu2f(unsigned short u) {
    union { __hip_bfloat16 h; unsigned short u; } cv; cv.u = u;
    return __bfloat162float(cv.h);
}
__device__ __forceinline__ unsigned int pk2(float a, float b) {
    return (unsigned int)f2bu(a) | ((unsigned int)f2bu(b) << 16);
}
// pack two f32 -> packed bf16 pair with round-half-up (cheap)
__device__ __forceinline__ unsigned int pk2_fast(float a, float b) {
    return ((__float_as_uint(a) + 0x8000u) >> 16) |
           ((__float_as_uint(b) + 0x8000u) & 0xFFFF0000u);
}
// raw v_exp_f32 — exp2f() without fast-math expands to a denorm-guard
// sequence (~12 extra VALU ops); attention scores never reach denormals.
__device__ __forceinline__ float fexp2(float x) {
    return __builtin_amdgcn_exp2f(x);
}
__device__ __forceinline__ float ld1d(const void* p, size_t idx, bool f32) {
    return f32 ? ((const float*)p)[idx] : bu2f(((const unsigned short*)p)[idx]);
}
// sum across the 4 quads (lane bits 4-5)
__device__ __forceinline__ float qsumq(float v) {
    v += __shfl_xor(v, 16); v += __shfl_xor(v, 32);
    return v;
}
// async global->LDS, 16 B per lane (GEMMs only — attn uses register prefetch
// because its per-tile barrier drains vmcnt(0) and exposes the DMA latency)
__device__ __forceinline__ void glds16(const unsigned short* g, unsigned short* l) {
    __builtin_amdgcn_global_load_lds(
        (const __attribute__((address_space(1))) unsigned int*)g,
        (__attribute__((address_space(3))) unsigned int*)l, 16, 0, 0);
}
// dtype detect, wave-local (identical result in every wave): sample 64 u16
// words of x; bf16 data -> ~all exponent fields sane; f32-as-u16 -> ~half.
__device__ __forceinline__ bool detect_f32(const unsigned short* q16) {
    int e = (q16[threadIdx.x & 63] >> 7) & 0xFF;
    bool sane = (e == 0) || (e >= 97 && e <= 157);
    unsigned long long m = __ballot(sane);
    return __popcll(m) < 56;   // true = f32 inputs
}

// ---------------------------------------------------------------------------
// One-pass f32->bf16 conversion of x, Wq..Wo, bq..bo into ws. Also publishes
// the dtype flag (block (0,0) of the x region) for the attn/out kernels.
// ---------------------------------------------------------------------------
__global__ __launch_bounds__(256) void cvt_bf16(
    const void* __restrict__ x,
    const void* __restrict__ Wq, const void* __restrict__ Wk,
    const void* __restrict__ Wv, const void* __restrict__ Wo,
    const void* __restrict__ bq, const void* __restrict__ bk,
    const void* __restrict__ bv, const void* __restrict__ bo,
    unsigned short* __restrict__ xw, unsigned short* __restrict__ Ww,
    unsigned short* __restrict__ bw, int* __restrict__ flag)
{
    const bool f32m = detect_f32((const unsigned short*)x);
    if (blockIdx.x == 0 && blockIdx.y == 0 && threadIdx.x == 0)
        *flag = f32m ? 1 : 0;
    const int y = blockIdx.y;
    const void* src; unsigned short* dst; int n;
    if (y == 0)      { src = x; dst = xw; n = M_ * E_; }
    else if (y <= 4) {
        src = (y == 1) ? Wq : (y == 2) ? Wk : (y == 3) ? Wv : Wo;
        dst = Ww + (size_t)(y - 1) * E_ * E_; n = E_ * E_;
    } else {
        src = (y == 5) ? bq : (y == 6) ? bk : (y == 7) ? bv : bo;
        dst = bw + (size_t)(y - 5) * E_; n = E_;
    }
    int i = (blockIdx.x * 256 + threadIdx.x) * 8;
    if (i >= n) return;
    if (f32m) {
        const float* s = (const float*)src + i;
        float4 f0 = *(const float4*)s, f1 = *(const float4*)(s + 4);
        union { unsigned int d[4]; s8b v; } u;
        u.d[0] = pk2(f0.x, f0.y); u.d[1] = pk2(f0.z, f0.w);
        u.d[2] = pk2(f1.x, f1.y); u.d[3] = pk2(f1.z, f1.w);
        *(s8b*)(dst + i) = u.v;
    } else {
        *(s8b*)(dst + i) = *(const s8b*)((const unsigned short*)src + i);
    }
}

// ---------------------------------------------------------------------------
// QKV projection, bf16 MFMA GEMM, XCD swizzle, glds staging (xor-swizzled),
// double-buffered single-barrier. p==2 (V) is written TRANSPOSED [N][D][T].
// R20: V epilogue is LDS-STAGED — the old path scattered 4B stores at
// stride-T_ (~64 cache lines per wave-store, ~2M L2 transactions for 8 MB).
// After the K-loop the 32 KB smem is dead; stage u32 t-pairs with an xor
// swizzle, then 16B coalesced stores (8 threads = one 128 B run).
// ---------------------------------------------------------------------------
__global__ __launch_bounds__(256, 3) void qkv_gemm(
    const unsigned short* __restrict__ xw, const unsigned short* __restrict__ Ww,
    const unsigned short* __restrict__ bw,
    unsigned short* __restrict__ qo, unsigned short* __restrict__ ko,
    unsigned short* __restrict__ vo)
{
    const int bid = blockIdx.x;            // 768 blocks
    const int r_ = bid & 7, s_ = bid >> 3;
    const int g = r_ + 8 * (s_ >> 3);      // group in [0,96): (m,p)
    const int e0 = (s_ & 7) * 128;
    const int m0 = (g & 31) * 128;
    const int p  = g >> 5;
    const unsigned short* W    = Ww + (size_t)p * E_ * E_;
    const unsigned short* bias = bw + (size_t)p * E_;
    const float scale = (p == 0) ? 0.125f * LOG2E : 1.0f;

    const int tid = threadIdx.x, w = tid >> 6, lane = tid & 63;
    const int quad = lane >> 4, lc = lane & 15;
    const int wx = w & 1, wy = w >> 1;

    // smem[0..1] = A dbuf, smem[2..3] = B dbuf; all 32 KB reused by the
    // V-epilogue staging tile (cst).
    __shared__ unsigned short smem[4][128 * 32];

    f4 acc[4][4];
    #pragma unroll
    for (int i = 0; i < 4; i++)
        #pragma unroll
        for (int j = 0; j < 4; j++) acc[i][j] = (f4){0.f, 0.f, 0.f, 0.f};

    const int gr = lane >> 2;
    const int gc = (lane & 3) ^ ((lane >> 2) & 3);
    const size_t aoff = (size_t)(m0 + w*32 + gr) * E_ + gc*8;
    const size_t boff = (size_t)(e0 + w*32 + gr) * E_ + gc*8;

    #pragma unroll
    for (int j = 0; j < 2; j++) {
        glds16(xw + aoff + (size_t)j*16*E_, &smem[0][(w*128 + j*64) * 8]);
        glds16(W  + boff + (size_t)j*16*E_, &smem[2][(w*128 + j*64) * 8]);
    }
    __syncthreads();

    const int fcA = quad ^ (lc & 3);
    for (int k0 = 0; k0 < E_; k0 += 32) {
        const int cur = (k0 >> 5) & 1;
        if (k0 + 32 < E_) {
            #pragma unroll
            for (int j = 0; j < 2; j++) {
                glds16(xw + aoff + (size_t)j*16*E_ + k0 + 32, &smem[cur^1][(w*128 + j*64) * 8]);
                glds16(W  + boff + (size_t)j*16*E_ + k0 + 32, &smem[2 + (cur^1)][(w*128 + j*64) * 8]);
            }
        }
        s8b af[4], bfr[4];
        #pragma unroll
        for (int i = 0; i < 4; i++)
            af[i]  = *(const s8b*)&smem[cur][((wy*64 + i*16 + lc)*4 + fcA) * 8];
        #pragma unroll
        for (int i = 0; i < 4; i++)
            bfr[i] = *(const s8b*)&smem[2 + cur][((wx*64 + i*16 + lc)*4 + fcA) * 8];
        #pragma unroll
        for (int ms = 0; ms < 4; ms++)
            #pragma unroll
            for (int ns = 0; ns < 4; ns++)
                acc[ms][ns] = MFMA_B16(af[ms], bfr[ns], acc[ms][ns]);
        __syncthreads();
    }

    float bias_v[4];
    #pragma unroll
    for (int ns = 0; ns < 4; ns++) bias_v[ns] = bu2f(bias[e0 + wx*64 + ns*16 + lc]);

    if (p < 2) {
        #pragma unroll
        for (int ms = 0; ms < 4; ms++)
            #pragma unroll
            for (int ns = 0; ns < 4; ns++)
                #pragma unroll
                for (int r2 = 0; r2 < 4; r2++) {
                    float val = (acc[ms][ns][r2] + bias_v[ns]) * scale;
                    float nb = __shfl_xor(val, 1);
                    if (!(lane & 1)) {
                        int m = m0 + wy*64 + ms*16 + quad*4 + r2;
                        int t = m >> 1, bb = m & 1;
                        int e = e0 + wx*64 + ns*16 + lc;
                        int h = e >> 6, d = e & 63;
                        unsigned short* dst = (p == 0) ? qo : ko;
                        *(unsigned int*)&dst[(((size_t)(bb*H_ + h) * T_ + t) << 6) + d] = pk2(val, nb);
                    }
                }
    } else {
        // ---- V epilogue, LDS-staged ----
        // cst[e_l][c ^ x]: c = bb*32 + tq (u32 t-pair index), x = (e_l&7)<<2.
        // Writes: 2-way bank alias (free); reads: conflict-free b128 rows.
        unsigned int* cst = (unsigned int*)&smem[0][0];   // 8192 u32 = 32 KB
        #pragma unroll
        for (int ms = 0; ms < 4; ms++) {
            const int tq = wy*16 + ms*4 + quad;           // [0,32)
            #pragma unroll
            for (int ns = 0; ns < 4; ns++) {
                const int e_l = wx*64 + ns*16 + lc;       // [0,128)
                const int x = (e_l & 7) << 2;
                float v0 = acc[ms][ns][0] + bias_v[ns];
                float v1 = acc[ms][ns][1] + bias_v[ns];
                float v2 = acc[ms][ns][2] + bias_v[ns];
                float v3 = acc[ms][ns][3] + bias_v[ns];
                cst[e_l*64 + ( tq       ^ x)] = pk2(v0, v2);   // bb = 0
                cst[e_l*64 + ((32 + tq) ^ x)] = pk2(v1, v3);   // bb = 1
            }
        }
        __syncthreads();
        #pragma unroll
        for (int i = 0; i < 8; i++) {
            const int li  = i*256 + tid;                  // [0,2048)
            const int e_l = li >> 4;
            const int bb  = (li >> 3) & 1;
            const int ch  = li & 7;                       // 16B chunk
            const int x   = (e_l & 7) << 2;
            uint4 vd = *(const uint4*)&cst[e_l*64 + ((bb*32 + ch*4) ^ x)];
            const int e = e0 + e_l, h = e >> 6, d = e & 63;
            const size_t du = ((size_t)(bb*H_ + h) * 64 + d) * (T_/2)
                              + (m0 >> 2) + ch*4;
            *(uint4*)((unsigned int*)vo + du) = vd;
        }
    }
}

// ---------------------------------------------------------------------------
// Flash attention with Shaw bias — R19 (best known): 8-wave 512-thr blocks,
// 128-row Q-tiles, KVBLK=64 dbuf, ONE barrier/tile, bijection-correct
// tile-order stagger (neutral but harmless), no setprio (R18: negative).
// ---------------------------------------------------------------------------
__global__ __launch_bounds__(512, 4) void attn_mfma(
    const unsigned short* __restrict__ q, const unsigned short* __restrict__ k,
    const unsigned short* __restrict__ v,
    const void* __restrict__ rk_t, const void* __restrict__ rv_t,
    unsigned short* __restrict__ aout, const int* __restrict__ flag)
{
    const bool f32m = (*flag != 0);
    const int bid = blockIdx.x;
    const int n = bid & 31, qt = bid >> 5;
    const int t0 = qt * 128;
    const int tid = threadIdx.x, w = tid >> 6, lane = tid & 63;
    const int quad = lane >> 4, lc = lane & 15;

    __shared__ unsigned short k_s[2][64 * 64];   // K[s][d] swizzled (buf0: rv^T later)
    __shared__ unsigned short v_s[2][64 * 64];   // V^T[d][s] swizzled
    __shared__ unsigned short p_s[8][16 * 72];   // per-wave P[t][s] / P_extra; rk staging
    __shared__ unsigned short qrk_s[128 * 36];   // qrk[t_local][r] bf16 (log2 dom.)
    __shared__ unsigned short diag16[128 * 33];  // e-values at |rel|<16, bf16
    __shared__ float st_L[128], st_R[128];

    const unsigned short* qn = q + ((size_t)n * T_ + t0) * D_;
    const unsigned short* kn = k + (size_t)n * T_ * D_;
    const unsigned short* vn = v + (size_t)n * D_ * T_;   // V^T [D][T]

    // Q fragments (B-operand for S^T): 16 rows per wave (t = w*16 + lc)
    s8b qa[2];
    #pragma unroll
    for (int kf = 0; kf < 2; kf++)
        qa[kf] = *(const s8b*)(qn + (size_t)(w*16 + lc) * D_ + kf*32 + quad*8);

    for (int i = tid; i < 128 * 33; i += 512) diag16[i] = 0;

    // stage rk (bf16, padded [48][72], rows>=33 zero) into p_s area
    unsigned int* rks = (unsigned int*)&p_s[0][0];
    for (int i = tid; i < 48 * 36; i += 512) {
        int r = i / 36, c2 = i % 36;
        unsigned int val = 0;
        if (r < 33 && c2 < 32)
            val = pk2(ld1d(rk_t, r*64 + 2*c2, f32m), ld1d(rk_t, r*64 + 2*c2 + 1, f32m));
        rks[i] = val;
    }
    __syncthreads();

    // qrk[t][r] = q[t] . rk[r] via MFMA (prologue-only); rows w*16..w*16+15
    for (int nt = 0; nt < 3; nt++) {
        s8b b0 = *(const s8b*)((const unsigned short*)rks + (nt*16 + lc)*72 + quad*8);
        s8b b1 = *(const s8b*)((const unsigned short*)rks + (nt*16 + lc)*72 + 32 + quad*8);
        f4 a = (f4){0.f, 0.f, 0.f, 0.f};
        a = MFMA_B16(qa[0], b0, a);
        a = MFMA_B16(qa[1], b1, a);
        #pragma unroll
        for (int r = 0; r < 4; r++) {
            float nb = __shfl_xor(a[r], 1);
            int col = nt*16 + lc;
            if (!(lane & 1) && col < 34)
                ((unsigned int*)qrk_s)[(w*16 + quad*4 + r)*18 + (col >> 1)] = pk2(a[r], nb);
        }
    }
    __syncthreads();   // rk staging (aliased with p_s) free after this

    // per-lane Shaw edge biases (t = w*16 + lc)
    const int t_l = w*16 + lc;
    const float qLn = bu2f(qrk_s[t_l*36 + 0]);
    const float qRn = bu2f(qrk_s[t_l*36 + 32]);
    float L_p = 0.f, R_p = 0.f;
    f4 O[4], lsN, lsL, lsR;
    lsN = (f4){0.f, 0.f, 0.f, 0.f};
    lsL = (f4){0.f, 0.f, 0.f, 0.f};
    lsR = (f4){0.f, 0.f, 0.f, 0.f};
    #pragma unroll
    for (int dt = 0; dt < 4; dt++) O[dt] = (f4){0.f, 0.f, 0.f, 0.f};
    const short ob = (short)0x3F80;   // bf16 1.0
    const s8b ones = { ob, ob, ob, ob, ob, ob, ob, ob };

    // staging mapping: 512 threads cover the 64x64 tile in ONE 16B/thread
    // round. row = w*8 + grr, source chunk xor-swizzled: phys = src ^ (row&7).
    const int grr = lane >> 3;
    const int gcc = (lane & 7) ^ grr;
    const size_t koff = (size_t)(w*8 + grr) * D_ + gcc*8;   // + (s0)*D_
    const size_t voff = (size_t)(w*8 + grr) * T_ + gcc*8;   // + s0

    // tile-order stagger: co-resident pair (bid, bid+256) -> opposite phase
    const int kts = ((bid >> 8) & 1) * 16;

    // first tile register prefetch + write buf 0
    s8b kr0 = *(const s8b*)(kn + koff + (size_t)(kts * 64) * D_);
    s8b vr0 = *(const s8b*)(vn + voff + kts * 64);
    *(s8b*)&k_s[0][(w*64 + lane) * 8] = kr0;
    *(s8b*)&v_s[0][(w*64 + lane) * 8] = vr0;
    __syncthreads();

    const int lc7 = lc & 7;
    for (int it = 0; it < 32; it++) {
        const int kt = (it + kts) & 31;
        const int s0 = kt * 64;
        const int cur = it & 1;
        if (it + 1 < 32) {   // issue next tile's global loads now
            const int s0n = ((it + 1 + kts) & 31) * 64;
            kr0 = *(const s8b*)(kn + koff + (size_t)s0n * D_);
            vr0 = *(const s8b*)(vn + voff + s0n);
        }

        const bool farL  = (s0 + 63 < t0 - 16);
        const bool farR  = (s0 > t0 + 143);
        const bool nearT = !farL && !farR;

        // K fragments (A-operand for S^T): K[s=st*16+lc][d]
        s8b ak[4][2];
        #pragma unroll
        for (int st = 0; st < 4; st++) {
            int row = st*16 + lc;
            ak[st][0] = *(const s8b*)&k_s[cur][(row*8 + (quad       ^ lc7)) * 8];
            ak[st][1] = *(const s8b*)&k_s[cur][(row*8 + ((4 + quad) ^ lc7)) * 8];
        }

        // S^T = K·Q^T (+ bias), exp2, pack b64 into P[t][s]
        #pragma unroll
        for (int st = 0; st < 4; st++) {
            f4 a;
            if (nearT) a = (f4){0.f, 0.f, 0.f, 0.f};
            else {
                float qb = farL ? qLn : qRn;
                a = (f4){qb, qb, qb, qb};
            }
            a = MFMA_B16(ak[st][0], qa[0], a);
            a = MFMA_B16(ak[st][1], qa[1], a);
            unsigned int lo, hi;
            if (nearT) {
                const int sb = s0 + st*16 + quad*4 - (t0 + t_l);
                unsigned short eb[4];
                #pragma unroll
                for (int r = 0; r < 4; r++) {
                    int rel = sb + r;
                    int rc = rel < -16 ? -16 : (rel > 16 ? 16 : rel);
                    float e = fexp2(a[r] + bu2f(qrk_s[t_l*36 + rc + 16]));
                    eb[r] = f2bu_fast(e);
                    if (rel <= -16)      L_p += e;
                    else if (rel >= 16)  R_p += e;
                    else                 diag16[t_l*33 + rel + 15] = eb[r];
                }
                lo = (unsigned int)eb[0] | ((unsigned int)eb[1] << 16);
                hi = (unsigned int)eb[2] | ((unsigned int)eb[3] << 16);
            } else {
                lo = pk2_fast(fexp2(a[0]), fexp2(a[1]));
                hi = pk2_fast(fexp2(a[2]), fexp2(a[3]));
            }
            *(uint2*)&p_s[w][lc*72 + st*16 + quad*4] = make_uint2(lo, hi);
        }

        // P fragments (B-operand): P[t=lc][s=quad*8+j]
        s8b pb[2];
        pb[0] = *(const s8b*)&p_s[w][lc*72 + quad*8];
        pb[1] = *(const s8b*)&p_s[w][lc*72 + 32 + quad*8];
        // column sums of P^T (= row sums of P) via ones-MFMA
        if (nearT) {
            lsN = MFMA_B16(ones, pb[0], lsN);
            lsN = MFMA_B16(ones, pb[1], lsN);
        } else if (farL) {
            lsL = MFMA_B16(ones, pb[0], lsL);
            lsL = MFMA_B16(ones, pb[1], lsL);
        } else {
            lsR = MFMA_B16(ones, pb[0], lsR);
            lsR = MFMA_B16(ones, pb[1], lsR);
        }
        // O^T += V^T · P^T
        #pragma unroll
        for (int dt = 0; dt < 4; dt++) {
            int row = dt*16 + lc;
            s8b a0 = *(const s8b*)&v_s[cur][(row*8 + (quad       ^ lc7)) * 8];
            s8b a1 = *(const s8b*)&v_s[cur][(row*8 + ((4 + quad) ^ lc7)) * 8];
            O[dt] = MFMA_B16(a0, pb[0], O[dt]);
            O[dt] = MFMA_B16(a1, pb[1], O[dt]);
        }

        if (it + 1 < 32) {   // write prefetched tile to the other buffer
            *(s8b*)&k_s[cur ^ 1][(w*64 + lane) * 8] = kr0;
            *(s8b*)&v_s[cur ^ 1][(w*64 + lane) * 8] = vr0;
        }
        __syncthreads();
    }

    // ---- epilogue: totals, relpos-V via rv^T·P_extra^T, normalize, store ----
    float l = lsN[0] + lsL[0] + lsR[0];
    float L = lsL[0] + qsumq(L_p);
    float R = lsR[0] + qsumq(R_p);
    const float linv = 1.f / l;
    if (quad == 0) { st_L[t_l] = L; st_R[t_l] = R; }
    // stage rv TRANSPOSED into k_s[0] with the SAME xor swizzle (r>=33 zero)
    {
        unsigned int* rvs = (unsigned int*)&k_s[0][0];
        for (int i = tid; i < 64 * 32; i += 512) {
            int d = i >> 5, dwL = i & 31;
            int r0 = dwL * 2, r1 = r0 + 1;
            float x0 = (r0 < 33) ? ld1d(rv_t, (size_t)r0 * 64 + d, f32m) : 0.f;
            float x1 = (r1 < 33) ? ld1d(rv_t, (size_t)r1 * 64 + d, f32m) : 0.f;
            int phys = d * 32 + ((dwL >> 2) ^ (d & 7)) * 4 + (dwL & 3);
            rvs[phys] = pk2(x0, x1);
        }
    }
    __syncthreads();
    // build P_extra[16][64] bf16 in own wave region (cols 33..63 = 0)
    for (int j = 0; j < 16; j++) {
        int c = lane;
        int row = w*16 + j;
        unsigned short pv;
        if (c == 0)        pv = f2bu(st_L[row]);
        else if (c == 32)  pv = f2bu(st_R[row]);
        else if (c < 32)   pv = diag16[row*33 + c - 1];
        else               pv = 0;
        p_s[w][j*72 + c] = pv;
    }
    // O^T += rv^T · P_extra^T
    s8b pe[2];
    pe[0] = *(const s8b*)&p_s[w][lc*72 + quad*8];
    pe[1] = *(const s8b*)&p_s[w][lc*72 + 32 + quad*8];
    #pragma unroll
    for (int dt = 0; dt < 4; dt++) {
        int row = dt*16 + lc;
        s8b a0 = *(const s8b*)&k_s[0][(row*8 + (quad       ^ lc7)) * 8];
        s8b a1 = *(const s8b*)&k_s[0][(row*8 + ((4 + quad) ^ lc7)) * 8];
        O[dt] = MFMA_B16(a0, pe[0], O[dt]);
        O[dt] = MFMA_B16(a1, pe[1], O[dt]);
    }
    // normalize + store bf16 [T][B][E] — packed 8B store, no shfl
    const int bb = n >> 4, h = n & 15;
    {
        int t_g = t0 + t_l;
        #pragma unroll
        for (int dt = 0; dt < 4; dt++) {
            float v0 = O[dt][0] * linv;
            float v1 = O[dt][1] * linv;
            float v2 = O[dt][2] * linv;
            float v3 = O[dt][3] * linv;
            int e = h*64 + dt*16 + quad*4;
            *(uint2*)&aout[((size_t)t_g * B_ + bb) * E_ + e] =
                make_uint2(pk2(v0, v1), pk2(v2, v3));
        }
    }
}

// ---------------------------------------------------------------------------
// Output projection, bf16 MFMA GEMM, XCD swizzle, glds staging, dbuf.
// ---------------------------------------------------------------------------
__global__ __launch_bounds__(256, 3) void out_gemm(
    const unsigned short* __restrict__ A,
    const unsigned short* __restrict__ Wob, const unsigned short* __restrict__ bob,
    void* __restrict__ out, const int* __restrict__ flag)
{
    const bool f32m = (*flag != 0);
    const int bid = blockIdx.x;            // 256 blocks
    const int r_ = bid & 7, s_ = bid >> 3;
    const int g = r_ + 8 * (s_ >> 3);
    const int m0 = g * 128;
    const int e0 = (s_ & 7) * 128;

    const int tid = threadIdx.x, w = tid >> 6, lane = tid & 63;
    const int quad = lane >> 4, lc = lane & 15;
    const int wx = w & 1, wy = w >> 1;

    __shared__ unsigned short a_s[2][128 * 32];
    __shared__ unsigned short b_s[2][128 * 32];

    f4 acc[4][4];
    #pragma unroll
    for (int i = 0; i < 4; i++)
        #pragma unroll
        for (int j = 0; j < 4; j++) acc[i][j] = (f4){0.f, 0.f, 0.f, 0.f};

    const int gr = lane >> 2;
    const int gc = (lane & 3) ^ ((lane >> 2) & 3);
    const size_t aoff = (size_t)(m0 + w*32 + gr) * E_ + gc*8;
    const size_t boff = (size_t)(e0 + w*32 + gr) * E_ + gc*8;

    #pragma unroll
    for (int j = 0; j < 2; j++) {
        glds16(A   + aoff + (size_t)j*16*E_, &a_s[0][(w*128 + j*64) * 8]);
        glds16(Wob + boff + (size_t)j*16*E_, &b_s[0][(w*128 + j*64) * 8]);
    }
    __syncthreads();

    const int fcA = quad ^ (lc & 3);
    for (int k0 = 0; k0 < E_; k0 += 32) {
        const int cur = (k0 >> 5) & 1;
        if (k0 + 32 < E_) {
            #pragma unroll
            for (int j = 0; j < 2; j++) {
                glds16(A   + aoff + (size_t)j*16*E_ + k0 + 32, &a_s[cur^1][(w*128 + j*64) * 8]);
                glds16(Wob + boff + (size_t)j*16*E_ + k0 + 32, &b_s[cur^1][(w*128 + j*64) * 8]);
            }
        }
        s8b af[4], bfr[4];
        #pragma unroll
        for (int i = 0; i < 4; i++)
            af[i]  = *(const s8b*)&a_s[cur][((wy*64 + i*16 + lc)*4 + fcA) * 8];
        #pragma unroll
        for (int i = 0; i < 4; i++)
            bfr[i] = *(const s8b*)&b_s[cur][((wx*64 + i*16 + lc)*4 + fcA) * 8];
        #pragma unroll
        for (int ms = 0; ms < 4; ms++)
            #pragma unroll
            for (int ns = 0; ns < 4; ns++)
                acc[ms][ns] = MFMA_B16(af[ms], bfr[ns], acc[ms][ns]);
        __syncthreads();
    }

    float bias_v[4];
    #pragma unroll
    for (int ns = 0; ns < 4; ns++) bias_v[ns] = bu2f(bob[e0 + wx*64 + ns*16 + lc]);

    #pragma unroll
    for (int ms = 0; ms < 4; ms++)
        #pragma unroll
        for (int ns = 0; ns < 4; ns++)
            #pragma unroll
            for (int r2 = 0; r2 < 4; r2++) {
                float val = acc[ms][ns][r2] + bias_v[ns];
                size_t m = m0 + wy*64 + ms*16 + quad*4 + r2;
                int e = e0 + wx*64 + ns*16 + lc;
                if (f32m) {
                    ((float*)out)[m * E_ + e] = val;
                } else {
                    float nb = __shfl_xor(val, 1);
                    if (!(lane & 1))
                        *(unsigned int*)&((unsigned short*)out)[m * E_ + e] = pk2(val, nb);
                }
            }
}

extern "C" void kernel_launch(void* const* d_in, const int* in_sizes, int n_in,
                              void* d_out, int out_size, void* d_ws, size_t ws_size,
                              hipStream_t stream) {
    const void* x  = d_in[0];
    const void* Wq = d_in[1];  const void* bq = d_in[2];
    const void* Wk = d_in[3];  const void* bk = d_in[4];
    const void* Wv = d_in[5];  const void* bv = d_in[6];
    const void* Wo = d_in[7];  const void* bo = d_in[8];
    const void* rk = d_in[9];  const void* rv = d_in[10];

    int* flag = (int*)d_ws;
    const size_t HTD = (size_t)NH_ * T_ * D_;        // 4,194,304 elems
    unsigned short* qw = (unsigned short*)((char*)d_ws + 256);
    unsigned short* kw = qw + HTD;
    unsigned short* vw = kw + HTD;                   // V^T [N][D][T] bf16
    unsigned short* aw = vw + HTD;                   // [4096][1024] bf16 pre-Wo
    unsigned short* xw = aw + (size_t)M_ * E_;       // x as bf16 (8 MB)
    unsigned short* Ww = xw + (size_t)M_ * E_;       // Wq,Wk,Wv,Wo bf16 (8 MB)
    unsigned short* bw = Ww + (size_t)4 * E_ * E_;   // bq,bk,bv,bo bf16 (8 KB)
    // ws use: ~48 MB

    cvt_bf16<<<dim3((M_*E_/8 + 255)/256, 9), 256, 0, stream>>>(
        x, Wq, Wk, Wv, Wo, bq, bk, bv, bo, xw, Ww, bw, flag);
    qkv_gemm<<<dim3(768), 256, 0, stream>>>(xw, Ww, bw, qw, kw, vw);
    attn_mfma<<<dim3(NH_ * (T_/128)), 512, 0, stream>>>(qw, kw, vw, rk, rv, aw, flag);
    out_gemm<<<dim3(256), 256, 0, stream>>>(aw, Ww + (size_t)3*E_*E_, bw + 3*E_,
                                            d_out, flag);
}

// Round 11
// 207.818 us; speedup vs baseline: 1.0782x; 1.0419x over previous
//
#include <hip/hip_runtime.h>
#include <hip/hip_bf16.h>
#include <math.h>

#define T_   2048
#define B_   2
#define E_   1024
#define H_   16
#define D_   64
#define NH_  32
#define M_   4096

typedef __attribute__((ext_vector_type(8))) short s8b;   // 8 bf16 (4 VGPRs)
typedef __attribute__((ext_vector_type(4))) float f4;    // 4 f32 acc

#define MFMA_B16(a,b,c) __builtin_amdgcn_mfma_f32_16x16x32_bf16(a,b,c,0,0,0)
#define LOG2E 1.44269504088896f

__device__ __forceinline__ unsigned short f2bu(float f) {
    union { __hip_bfloat16 h; unsigned short u; } cv;
    cv.h = __float2bfloat16(f);
    return cv.u;
}
// fast bf16: round-half-up truncation (positive finite values) — 2 VALU ops
__device__ __forceinline__ unsigned short f2bu_fast(float f) {
    return (unsigned short)((__float_as_uint(f) + 0x8000u) >> 16);
}
__device__ __forceinline__ float bu2f(unsigned short u) {
    union { __hip_bfloat16 h; unsigned short u; } cv; cv.u = u;
    return __bfloat162float(cv.h);
}
__device__ __forceinline__ unsigned int pk2(float a, float b) {
    return (unsigned int)f2bu(a) | ((unsigned int)f2bu(b) << 16);
}
// pack two f32 -> packed bf16 pair with round-half-up (cheap)
__device__ __forceinline__ unsigned int pk2_fast(float a, float b) {
    return ((__float_as_uint(a) + 0x8000u) >> 16) |
           ((__float_as_uint(b) + 0x8000u) & 0xFFFF0000u);
}
// raw v_exp_f32 — exp2f() without fast-math expands to a denorm-guard
// sequence (~12 extra VALU ops); attention scores never reach denormals.
__device__ __forceinline__ float fexp2(float x) {
    return __builtin_amdgcn_exp2f(x);
}
__device__ __forceinline__ float ld1d(const void* p, size_t idx, bool f32) {
    return f32 ? ((const float*)p)[idx] : bu2f(((const unsigned short*)p)[idx]);
}
// sum across the 4 quads (lane bits 4-5)
__device__ __forceinline__ float qsumq(float v) {
    v += __shfl_xor(v, 16); v += __shfl_xor(v, 32);
    return v;
}
// async global->LDS, 16 B per lane (GEMMs only — attn uses register prefetch
// because its per-tile barrier drains vmcnt(0) and exposes the DMA latency)
__device__ __forceinline__ void glds16(const unsigned short* g, unsigned short* l) {
    __builtin_amdgcn_global_load_lds(
        (const __attribute__((address_space(1))) unsigned int*)g,
        (__attribute__((address_space(3))) unsigned int*)l, 16, 0, 0);
}
// dtype detect, wave-local (identical result in every wave): sample 64 u16
// words of x; bf16 data -> ~all exponent fields sane; f32-as-u16 -> ~half.
__device__ __forceinline__ bool detect_f32(const unsigned short* q16) {
    int e = (q16[threadIdx.x & 63] >> 7) & 0xFF;
    bool sane = (e == 0) || (e >= 97 && e <= 157);
    unsigned long long m = __ballot(sane);
    return __popcll(m) < 56;   // true = f32 inputs
}

// ---------------------------------------------------------------------------
// One-pass f32->bf16 conversion of x, Wq..Wo, bq..bo into ws. R21: exact 1D
// grid (4100 blocks vs 18432 — the old 2D grid launched 14.3K dead blocks
// that each ran detect_f32 + return). Also publishes the dtype flag.
// ---------------------------------------------------------------------------
__global__ __launch_bounds__(256) void cvt_bf16(
    const void* __restrict__ x,
    const void* __restrict__ Wq, const void* __restrict__ Wk,
    const void* __restrict__ Wv, const void* __restrict__ Wo,
    const void* __restrict__ bq, const void* __restrict__ bk,
    const void* __restrict__ bv, const void* __restrict__ bo,
    unsigned short* __restrict__ xw, unsigned short* __restrict__ Ww,
    unsigned short* __restrict__ bw, int* __restrict__ flag)
{
    const bool f32m = detect_f32((const unsigned short*)x);
    const int bid = blockIdx.x;
    if (bid == 0 && threadIdx.x == 0)
        *flag = f32m ? 1 : 0;
    int y, lb;
    if (bid < 2048)       { y = 0;                      lb = bid; }
    else if (bid < 4096)  { y = 1 + ((bid - 2048) >> 9); lb = (bid - 2048) & 511; }
    else                  { y = 5 + (bid - 4096);        lb = 0; }
    const void* src; unsigned short* dst; int n;
    if (y == 0)      { src = x; dst = xw; n = M_ * E_; }
    else if (y <= 4) {
        src = (y == 1) ? Wq : (y == 2) ? Wk : (y == 3) ? Wv : Wo;
        dst = Ww + (size_t)(y - 1) * E_ * E_; n = E_ * E_;
    } else {
        src = (y == 5) ? bq : (y == 6) ? bk : (y == 7) ? bv : bo;
        dst = bw + (size_t)(y - 5) * E_; n = E_;
    }
    int i = (lb * 256 + threadIdx.x) * 8;
    if (i >= n) return;
    if (f32m) {
        const float* s = (const float*)src + i;
        float4 f0 = *(const float4*)s, f1 = *(const float4*)(s + 4);
        union { unsigned int d[4]; s8b v; } u;
        u.d[0] = pk2(f0.x, f0.y); u.d[1] = pk2(f0.z, f0.w);
        u.d[2] = pk2(f1.x, f1.y); u.d[3] = pk2(f1.z, f1.w);
        *(s8b*)(dst + i) = u.v;
    } else {
        *(s8b*)(dst + i) = *(const s8b*)((const unsigned short*)src + i);
    }
}

// ---------------------------------------------------------------------------
// QKV projection, bf16 MFMA GEMM, XCD swizzle, glds staging (xor-swizzled),
// double-buffered single-barrier. p==2 (V) written TRANSPOSED [N][D][T] via
// LDS-staged coalesced stores (R20). R21: Q/K epilogue ALSO LDS-staged —
// old path stored 32B runs over 4 rows/instr; staged path emits full 128B
// runs (8 threads per (bb,h,t) row).
// ---------------------------------------------------------------------------
__global__ __launch_bounds__(256, 3) void qkv_gemm(
    const unsigned short* __restrict__ xw, const unsigned short* __restrict__ Ww,
    const unsigned short* __restrict__ bw,
    unsigned short* __restrict__ qo, unsigned short* __restrict__ ko,
    unsigned short* __restrict__ vo)
{
    const int bid = blockIdx.x;            // 768 blocks
    const int r_ = bid & 7, s_ = bid >> 3;
    const int g = r_ + 8 * (s_ >> 3);      // group in [0,96): (m,p)
    const int e0 = (s_ & 7) * 128;
    const int m0 = (g & 31) * 128;
    const int p  = g >> 5;
    const unsigned short* W    = Ww + (size_t)p * E_ * E_;
    const unsigned short* bias = bw + (size_t)p * E_;
    const float scale = (p == 0) ? 0.125f * LOG2E : 1.0f;

    const int tid = threadIdx.x, w = tid >> 6, lane = tid & 63;
    const int quad = lane >> 4, lc = lane & 15;
    const int wx = w & 1, wy = w >> 1;

    // smem[0..1] = A dbuf, smem[2..3] = B dbuf; all 32 KB reused by the
    // epilogue staging tile (cst).
    __shared__ unsigned short smem[4][128 * 32];

    f4 acc[4][4];
    #pragma unroll
    for (int i = 0; i < 4; i++)
        #pragma unroll
        for (int j = 0; j < 4; j++) acc[i][j] = (f4){0.f, 0.f, 0.f, 0.f};

    const int gr = lane >> 2;
    const int gc = (lane & 3) ^ ((lane >> 2) & 3);
    const size_t aoff = (size_t)(m0 + w*32 + gr) * E_ + gc*8;
    const size_t boff = (size_t)(e0 + w*32 + gr) * E_ + gc*8;

    #pragma unroll
    for (int j = 0; j < 2; j++) {
        glds16(xw + aoff + (size_t)j*16*E_, &smem[0][(w*128 + j*64) * 8]);
        glds16(W  + boff + (size_t)j*16*E_, &smem[2][(w*128 + j*64) * 8]);
    }
    __syncthreads();

    const int fcA = quad ^ (lc & 3);
    for (int k0 = 0; k0 < E_; k0 += 32) {
        const int cur = (k0 >> 5) & 1;
        if (k0 + 32 < E_) {
            #pragma unroll
            for (int j = 0; j < 2; j++) {
                glds16(xw + aoff + (size_t)j*16*E_ + k0 + 32, &smem[cur^1][(w*128 + j*64) * 8]);
                glds16(W  + boff + (size_t)j*16*E_ + k0 + 32, &smem[2 + (cur^1)][(w*128 + j*64) * 8]);
            }
        }
        s8b af[4], bfr[4];
        #pragma unroll
        for (int i = 0; i < 4; i++)
            af[i]  = *(const s8b*)&smem[cur][((wy*64 + i*16 + lc)*4 + fcA) * 8];
        #pragma unroll
        for (int i = 0; i < 4; i++)
            bfr[i] = *(const s8b*)&smem[2 + cur][((wx*64 + i*16 + lc)*4 + fcA) * 8];
        #pragma unroll
        for (int ms = 0; ms < 4; ms++)
            #pragma unroll
            for (int ns = 0; ns < 4; ns++)
                acc[ms][ns] = MFMA_B16(af[ms], bfr[ns], acc[ms][ns]);
        __syncthreads();
    }

    float bias_v[4];
    #pragma unroll
    for (int ns = 0; ns < 4; ns++) bias_v[ns] = bu2f(bias[e0 + wx*64 + ns*16 + lc]);

    unsigned int* cst = (unsigned int*)&smem[0][0];   // 8192 u32 = 32 KB
    if (p < 2) {
        // ---- Q/K epilogue, LDS-staged ----
        // row = (bb*2 + h_local)*64 + tq  (256 rows x 32 u32), col = d>>1.
        #pragma unroll
        for (int ms = 0; ms < 4; ms++)
            #pragma unroll
            for (int ns = 0; ns < 4; ns++)
                #pragma unroll
                for (int r2 = 0; r2 < 4; r2++) {
                    float val = (acc[ms][ns][r2] + bias_v[ns]) * scale;
                    float nb = __shfl_xor(val, 1);
                    if (!(lane & 1)) {
                        int mi = wy*64 + ms*16 + quad*4 + r2;     // 0..127
                        int ei = wx*64 + ns*16 + lc;              // 0..127, even
                        int row = ((mi & 1) * 2 + (ei >> 6)) * 64 + (mi >> 1);
                        int col = (ei & 63) >> 1;                 // 0..31
                        cst[row*32 + (col ^ ((row & 7) << 2))] = pk2(val, nb);
                    }
                }
        __syncthreads();
        unsigned int* dst32 = (unsigned int*)((p == 0) ? qo : ko);
        #pragma unroll
        for (int i = 0; i < 8; i++) {
            const int li  = i*256 + tid;              // 0..2047
            const int row = li >> 3;                  // 0..255
            const int ch  = li & 7;                   // 16B chunk
            uint4 vd = *(const uint4*)&cst[row*32 + ((ch*4) ^ ((row & 7) << 2))];
            const int bb = row >> 7, hh = (row >> 6) & 1, tq = row & 63;
            const size_t du = (((size_t)(bb*H_ + (e0 >> 6) + hh) * T_
                                + (m0 >> 1) + tq) << 5) + ch*4;
            *(uint4*)&dst32[du] = vd;
        }
    } else {
        // ---- V epilogue, LDS-staged (R20) ----
        #pragma unroll
        for (int ms = 0; ms < 4; ms++) {
            const int tq = wy*16 + ms*4 + quad;           // [0,32)
            #pragma unroll
            for (int ns = 0; ns < 4; ns++) {
                const int e_l = wx*64 + ns*16 + lc;       // [0,128)
                const int x = (e_l & 7) << 2;
                float v0 = acc[ms][ns][0] + bias_v[ns];
                float v1 = acc[ms][ns][1] + bias_v[ns];
                float v2 = acc[ms][ns][2] + bias_v[ns];
                float v3 = acc[ms][ns][3] + bias_v[ns];
                cst[e_l*64 + ( tq       ^ x)] = pk2(v0, v2);   // bb = 0
                cst[e_l*64 + ((32 + tq) ^ x)] = pk2(v1, v3);   // bb = 1
            }
        }
        __syncthreads();
        #pragma unroll
        for (int i = 0; i < 8; i++) {
            const int li  = i*256 + tid;                  // [0,2048)
            const int e_l = li >> 4;
            const int bb  = (li >> 3) & 1;
            const int ch  = li & 7;                       // 16B chunk
            const int x   = (e_l & 7) << 2;
            uint4 vd = *(const uint4*)&cst[e_l*64 + ((bb*32 + ch*4) ^ x)];
            const int e = e0 + e_l, h = e >> 6, d = e & 63;
            const size_t du = ((size_t)(bb*H_ + h) * 64 + d) * (T_/2)
                              + (m0 >> 2) + ch*4;
            *(uint4*)((unsigned int*)vo + du) = vd;
        }
    }
}

// ---------------------------------------------------------------------------
// Flash attention with Shaw bias — R19 (best known): 8-wave 512-thr blocks,
// 128-row Q-tiles, KVBLK=64 dbuf, ONE barrier/tile, bijection-correct
// tile-order stagger (neutral but harmless), no setprio (R18: negative).
// Known regime (R20 analysis): ~76% LDS-BW-bound.
// ---------------------------------------------------------------------------
__global__ __launch_bounds__(512, 4) void attn_mfma(
    const unsigned short* __restrict__ q, const unsigned short* __restrict__ k,
    const unsigned short* __restrict__ v,
    const void* __restrict__ rk_t, const void* __restrict__ rv_t,
    unsigned short* __restrict__ aout, const int* __restrict__ flag)
{
    const bool f32m = (*flag != 0);
    const int bid = blockIdx.x;
    const int n = bid & 31, qt = bid >> 5;
    const int t0 = qt * 128;
    const int tid = threadIdx.x, w = tid >> 6, lane = tid & 63;
    const int quad = lane >> 4, lc = lane & 15;

    __shared__ unsigned short k_s[2][64 * 64];   // K[s][d] swizzled (buf0: rv^T later)
    __shared__ unsigned short v_s[2][64 * 64];   // V^T[d][s] swizzled
    __shared__ unsigned short p_s[8][16 * 72];   // per-wave P[t][s] / P_extra; rk staging
    __shared__ unsigned short qrk_s[128 * 36];   // qrk[t_local][r] bf16 (log2 dom.)
    __shared__ unsigned short diag16[128 * 33];  // e-values at |rel|<16, bf16
    __shared__ float st_L[128], st_R[128];

    const unsigned short* qn = q + ((size_t)n * T_ + t0) * D_;
    const unsigned short* kn = k + (size_t)n * T_ * D_;
    const unsigned short* vn = v + (size_t)n * D_ * T_;   // V^T [D][T]

    // Q fragments (B-operand for S^T): 16 rows per wave (t = w*16 + lc)
    s8b qa[2];
    #pragma unroll
    for (int kf = 0; kf < 2; kf++)
        qa[kf] = *(const s8b*)(qn + (size_t)(w*16 + lc) * D_ + kf*32 + quad*8);

    for (int i = tid; i < 128 * 33; i += 512) diag16[i] = 0;

    // stage rk (bf16, padded [48][72], rows>=33 zero) into p_s area
    unsigned int* rks = (unsigned int*)&p_s[0][0];
    for (int i = tid; i < 48 * 36; i += 512) {
        int r = i / 36, c2 = i % 36;
        unsigned int val = 0;
        if (r < 33 && c2 < 32)
            val = pk2(ld1d(rk_t, r*64 + 2*c2, f32m), ld1d(rk_t, r*64 + 2*c2 + 1, f32m));
        rks[i] = val;
    }
    __syncthreads();

    // qrk[t][r] = q[t] . rk[r] via MFMA (prologue-only); rows w*16..w*16+15
    for (int nt = 0; nt < 3; nt++) {
        s8b b0 = *(const s8b*)((const unsigned short*)rks + (nt*16 + lc)*72 + quad*8);
        s8b b1 = *(const s8b*)((const unsigned short*)rks + (nt*16 + lc)*72 + 32 + quad*8);
        f4 a = (f4){0.f, 0.f, 0.f, 0.f};
        a = MFMA_B16(qa[0], b0, a);
        a = MFMA_B16(qa[1], b1, a);
        #pragma unroll
        for (int r = 0; r < 4; r++) {
            float nb = __shfl_xor(a[r], 1);
            int col = nt*16 + lc;
            if (!(lane & 1) && col < 34)
                ((unsigned int*)qrk_s)[(w*16 + quad*4 + r)*18 + (col >> 1)] = pk2(a[r], nb);
        }
    }
    __syncthreads();   // rk staging (aliased with p_s) free after this

    // per-lane Shaw edge biases (t = w*16 + lc)
    const int t_l = w*16 + lc;
    const float qLn = bu2f(qrk_s[t_l*36 + 0]);
    const float qRn = bu2f(qrk_s[t_l*36 + 32]);
    float L_p = 0.f, R_p = 0.f;
    f4 O[4], lsN, lsL, lsR;
    lsN = (f4){0.f, 0.f, 0.f, 0.f};
    lsL = (f4){0.f, 0.f, 0.f, 0.f};
    lsR = (f4){0.f, 0.f, 0.f, 0.f};
    #pragma unroll
    for (int dt = 0; dt < 4; dt++) O[dt] = (f4){0.f, 0.f, 0.f, 0.f};
    const short ob = (short)0x3F80;   // bf16 1.0
    const s8b ones = { ob, ob, ob, ob, ob, ob, ob, ob };

    // staging mapping: 512 threads cover the 64x64 tile in ONE 16B/thread
    // round. row = w*8 + grr, source chunk xor-swizzled: phys = src ^ (row&7).
    const int grr = lane >> 3;
    const int gcc = (lane & 7) ^ grr;
    const size_t koff = (size_t)(w*8 + grr) * D_ + gcc*8;   // + (s0)*D_
    const size_t voff = (size_t)(w*8 + grr) * T_ + gcc*8;   // + s0

    // tile-order stagger: co-resident pair (bid, bid+256) -> opposite phase
    const int kts = ((bid >> 8) & 1) * 16;

    // first tile register prefetch + write buf 0
    s8b kr0 = *(const s8b*)(kn + koff + (size_t)(kts * 64) * D_);
    s8b vr0 = *(const s8b*)(vn + voff + kts * 64);
    *(s8b*)&k_s[0][(w*64 + lane) * 8] = kr0;
    *(s8b*)&v_s[0][(w*64 + lane) * 8] = vr0;
    __syncthreads();

    const int lc7 = lc & 7;
    for (int it = 0; it < 32; it++) {
        const int kt = (it + kts) & 31;
        const int s0 = kt * 64;
        const int cur = it & 1;
        if (it + 1 < 32) {   // issue next tile's global loads now
            const int s0n = ((it + 1 + kts) & 31) * 64;
            kr0 = *(const s8b*)(kn + koff + (size_t)s0n * D_);
            vr0 = *(const s8b*)(vn + voff + s0n);
        }

        const bool farL  = (s0 + 63 < t0 - 16);
        const bool farR  = (s0 > t0 + 143);
        const bool nearT = !farL && !farR;

        // K fragments (A-operand for S^T): K[s=st*16+lc][d]
        s8b ak[4][2];
        #pragma unroll
        for (int st = 0; st < 4; st++) {
            int row = st*16 + lc;
            ak[st][0] = *(const s8b*)&k_s[cur][(row*8 + (quad       ^ lc7)) * 8];
            ak[st][1] = *(const s8b*)&k_s[cur][(row*8 + ((4 + quad) ^ lc7)) * 8];
        }

        // S^T = K·Q^T (+ bias), exp2, pack b64 into P[t][s]
        #pragma unroll
        for (int st = 0; st < 4; st++) {
            f4 a;
            if (nearT) a = (f4){0.f, 0.f, 0.f, 0.f};
            else {
                float qb = farL ? qLn : qRn;
                a = (f4){qb, qb, qb, qb};
            }
            a = MFMA_B16(ak[st][0], qa[0], a);
            a = MFMA_B16(ak[st][1], qa[1], a);
            unsigned int lo, hi;
            if (nearT) {
                const int sb = s0 + st*16 + quad*4 - (t0 + t_l);
                unsigned short eb[4];
                #pragma unroll
                for (int r = 0; r < 4; r++) {
                    int rel = sb + r;
                    int rc = rel < -16 ? -16 : (rel > 16 ? 16 : rel);
                    float e = fexp2(a[r] + bu2f(qrk_s[t_l*36 + rc + 16]));
                    eb[r] = f2bu_fast(e);
                    if (rel <= -16)      L_p += e;
                    else if (rel >= 16)  R_p += e;
                    else                 diag16[t_l*33 + rel + 15] = eb[r];
                }
                lo = (unsigned int)eb[0] | ((unsigned int)eb[1] << 16);
                hi = (unsigned int)eb[2] | ((unsigned int)eb[3] << 16);
            } else {
                lo = pk2_fast(fexp2(a[0]), fexp2(a[1]));
                hi = pk2_fast(fexp2(a[2]), fexp2(a[3]));
            }
            *(uint2*)&p_s[w][lc*72 + st*16 + quad*4] = make_uint2(lo, hi);
        }

        // P fragments (B-operand): P[t=lc][s=quad*8+j]
        s8b pb[2];
        pb[0] = *(const s8b*)&p_s[w][lc*72 + quad*8];
        pb[1] = *(const s8b*)&p_s[w][lc*72 + 32 + quad*8];
        // column sums of P^T (= row sums of P) via ones-MFMA
        if (nearT) {
            lsN = MFMA_B16(ones, pb[0], lsN);
            lsN = MFMA_B16(ones, pb[1], lsN);
        } else if (farL) {
            lsL = MFMA_B16(ones, pb[0], lsL);
            lsL = MFMA_B16(ones, pb[1], lsL);
        } else {
            lsR = MFMA_B16(ones, pb[0], lsR);
            lsR = MFMA_B16(ones, pb[1], lsR);
        }
        // O^T += V^T · P^T
        #pragma unroll
        for (int dt = 0; dt < 4; dt++) {
            int row = dt*16 + lc;
            s8b a0 = *(const s8b*)&v_s[cur][(row*8 + (quad       ^ lc7)) * 8];
            s8b a1 = *(const s8b*)&v_s[cur][(row*8 + ((4 + quad) ^ lc7)) * 8];
            O[dt] = MFMA_B16(a0, pb[0], O[dt]);
            O[dt] = MFMA_B16(a1, pb[1], O[dt]);
        }

        if (it + 1 < 32) {   // write prefetched tile to the other buffer
            *(s8b*)&k_s[cur ^ 1][(w*64 + lane) * 8] = kr0;
            *(s8b*)&v_s[cur ^ 1][(w*64 + lane) * 8] = vr0;
        }
        __syncthreads();
    }

    // ---- epilogue: totals, relpos-V via rv^T·P_extra^T, normalize, store ----
    float l = lsN[0] + lsL[0] + lsR[0];
    float L = lsL[0] + qsumq(L_p);
    float R = lsR[0] + qsumq(R_p);
    const float linv = 1.f / l;
    if (quad == 0) { st_L[t_l] = L; st_R[t_l] = R; }
    // stage rv TRANSPOSED into k_s[0] with the SAME xor swizzle (r>=33 zero)
    {
        unsigned int* rvs = (unsigned int*)&k_s[0][0];
        for (int i = tid; i < 64 * 32; i += 512) {
            int d = i >> 5, dwL = i & 31;
            int r0 = dwL * 2, r1 = r0 + 1;
            float x0 = (r0 < 33) ? ld1d(rv_t, (size_t)r0 * 64 + d, f32m) : 0.f;
            float x1 = (r1 < 33) ? ld1d(rv_t, (size_t)r1 * 64 + d, f32m) : 0.f;
            int phys = d * 32 + ((dwL >> 2) ^ (d & 7)) * 4 + (dwL & 3);
            rvs[phys] = pk2(x0, x1);
        }
    }
    __syncthreads();
    // build P_extra[16][64] bf16 in own wave region (cols 33..63 = 0)
    for (int j = 0; j < 16; j++) {
        int c = lane;
        int row = w*16 + j;
        unsigned short pv;
        if (c == 0)        pv = f2bu(st_L[row]);
        else if (c == 32)  pv = f2bu(st_R[row]);
        else if (c < 32)   pv = diag16[row*33 + c - 1];
        else               pv = 0;
        p_s[w][j*72 + c] = pv;
    }
    // O^T += rv^T · P_extra^T
    s8b pe[2];
    pe[0] = *(const s8b*)&p_s[w][lc*72 + quad*8];
    pe[1] = *(const s8b*)&p_s[w][lc*72 + 32 + quad*8];
    #pragma unroll
    for (int dt = 0; dt < 4; dt++) {
        int row = dt*16 + lc;
        s8b a0 = *(const s8b*)&k_s[0][(row*8 + (quad       ^ lc7)) * 8];
        s8b a1 = *(const s8b*)&k_s[0][(row*8 + ((4 + quad) ^ lc7)) * 8];
        O[dt] = MFMA_B16(a0, pe[0], O[dt]);
        O[dt] = MFMA_B16(a1, pe[1], O[dt]);
    }
    // normalize + store bf16 [T][B][E] — packed 8B store, no shfl
    const int bb = n >> 4, h = n & 15;
    {
        int t_g = t0 + t_l;
        #pragma unroll
        for (int dt = 0; dt < 4; dt++) {
            float v0 = O[dt][0] * linv;
            float v1 = O[dt][1] * linv;
            float v2 = O[dt][2] * linv;
            float v3 = O[dt][3] * linv;
            int e = h*64 + dt*16 + quad*4;
            *(uint2*)&aout[((size_t)t_g * B_ + bb) * E_ + e] =
                make_uint2(pk2(v0, v1), pk2(v2, v3));
        }
    }
}

// ---------------------------------------------------------------------------
// Output projection, bf16 MFMA GEMM, XCD swizzle, glds staging, dbuf.
// R21: bf16 epilogue LDS-staged (same pattern as qkv Q/K); f32 path keeps
// direct stores (already 64B runs).
// ---------------------------------------------------------------------------
__global__ __launch_bounds__(256, 3) void out_gemm(
    const unsigned short* __restrict__ A,
    const unsigned short* __restrict__ Wob, const unsigned short* __restrict__ bob,
    void* __restrict__ out, const int* __restrict__ flag)
{
    const bool f32m = (*flag != 0);
    const int bid = blockIdx.x;            // 256 blocks
    const int r_ = bid & 7, s_ = bid >> 3;
    const int g = r_ + 8 * (s_ >> 3);
    const int m0 = g * 128;
    const int e0 = (s_ & 7) * 128;

    const int tid = threadIdx.x, w = tid >> 6, lane = tid & 63;
    const int quad = lane >> 4, lc = lane & 15;
    const int wx = w & 1, wy = w >> 1;

    __shared__ unsigned short smem[4][128 * 32];

    f4 acc[4][4];
    #pragma unroll
    for (int i = 0; i < 4; i++)
        #pragma unroll
        for (int j = 0; j < 4; j++) acc[i][j] = (f4){0.f, 0.f, 0.f, 0.f};

    const int gr = lane >> 2;
    const int gc = (lane & 3) ^ ((lane >> 2) & 3);
    const size_t aoff = (size_t)(m0 + w*32 + gr) * E_ + gc*8;
    const size_t boff = (size_t)(e0 + w*32 + gr) * E_ + gc*8;

    #pragma unroll
    for (int j = 0; j < 2; j++) {
        glds16(A   + aoff + (size_t)j*16*E_, &smem[0][(w*128 + j*64) * 8]);
        glds16(Wob + boff + (size_t)j*16*E_, &smem[2][(w*128 + j*64) * 8]);
    }
    __syncthreads();

    const int fcA = quad ^ (lc & 3);
    for (int k0 = 0; k0 < E_; k0 += 32) {
        const int cur = (k0 >> 5) & 1;
        if (k0 + 32 < E_) {
            #pragma unroll
            for (int j = 0; j < 2; j++) {
                glds16(A   + aoff + (size_t)j*16*E_ + k0 + 32, &smem[cur^1][(w*128 + j*64) * 8]);
                glds16(Wob + boff + (size_t)j*16*E_ + k0 + 32, &smem[2 + (cur^1)][(w*128 + j*64) * 8]);
            }
        }
        s8b af[4], bfr[4];
        #pragma unroll
        for (int i = 0; i < 4; i++)
            af[i]  = *(const s8b*)&smem[cur][((wy*64 + i*16 + lc)*4 + fcA) * 8];
        #pragma unroll
        for (int i = 0; i < 4; i++)
            bfr[i] = *(const s8b*)&smem[2 + cur][((wx*64 + i*16 + lc)*4 + fcA) * 8];
        #pragma unroll
        for (int ms = 0; ms < 4; ms++)
            #pragma unroll
            for (int ns = 0; ns < 4; ns++)
                acc[ms][ns] = MFMA_B16(af[ms], bfr[ns], acc[ms][ns]);
        __syncthreads();
    }

    float bias_v[4];
    #pragma unroll
    for (int ns = 0; ns < 4; ns++) bias_v[ns] = bu2f(bob[e0 + wx*64 + ns*16 + lc]);

    if (f32m) {
        #pragma unroll
        for (int ms = 0; ms < 4; ms++)
            #pragma unroll
            for (int ns = 0; ns < 4; ns++)
                #pragma unroll
                for (int r2 = 0; r2 < 4; r2++) {
                    float val = acc[ms][ns][r2] + bias_v[ns];
                    size_t m = m0 + wy*64 + ms*16 + quad*4 + r2;
                    int e = e0 + wx*64 + ns*16 + lc;
                    ((float*)out)[m * E_ + e] = val;
                }
    } else {
        // bf16 epilogue, LDS-staged: rows = mi (128), cols = ei>>1 (64 u32)
        unsigned int* cst = (unsigned int*)&smem[0][0];   // 8192 u32
        #pragma unroll
        for (int ms = 0; ms < 4; ms++)
            #pragma unroll
            for (int ns = 0; ns < 4; ns++)
                #pragma unroll
                for (int r2 = 0; r2 < 4; r2++) {
                    float val = acc[ms][ns][r2] + bias_v[ns];
                    float nb = __shfl_xor(val, 1);
                    if (!(lane & 1)) {
                        int mi = wy*64 + ms*16 + quad*4 + r2;   // 0..127
                        int ei = wx*64 + ns*16 + lc;            // even
                        int col = ei >> 1;                      // 0..63
                        cst[mi*64 + (col ^ ((mi & 7) << 2))] = pk2(val, nb);
                    }
                }
        __syncthreads();
        unsigned int* dst32 = (unsigned int*)out;
        #pragma unroll
        for (int i = 0; i < 8; i++) {
            const int li  = i*256 + tid;              // 0..2047
            const int row = li >> 4;                  // 0..127
            const int ch  = li & 15;                  // 16 chunks x 16B
            uint4 vd = *(const uint4*)&cst[row*64 + ((ch*4) ^ ((row & 7) << 2))];
            const size_t du = ((size_t)(m0 + row) * E_ + e0) / 2 + ch*4;
            *(uint4*)&dst32[du] = vd;
        }
    }
}

extern "C" void kernel_launch(void* const* d_in, const int* in_sizes, int n_in,
                              void* d_out, int out_size, void* d_ws, size_t ws_size,
                              hipStream_t stream) {
    const void* x  = d_in[0];
    const void* Wq = d_in[1];  const void* bq = d_in[2];
    const void* Wk = d_in[3];  const void* bk = d_in[4];
    const void* Wv = d_in[5];  const void* bv = d_in[6];
    const void* Wo = d_in[7];  const void* bo = d_in[8];
    const void* rk = d_in[9];  const void* rv = d_in[10];

    int* flag = (int*)d_ws;
    const size_t HTD = (size_t)NH_ * T_ * D_;        // 4,194,304 elems
    unsigned short* qw = (unsigned short*)((char*)d_ws + 256);
    unsigned short* kw = qw + HTD;
    unsigned short* vw = kw + HTD;                   // V^T [N][D][T] bf16
    unsigned short* aw = vw + HTD;                   // [4096][1024] bf16 pre-Wo
    unsigned short* xw = aw + (size_t)M_ * E_;       // x as bf16 (8 MB)
    unsigned short* Ww = xw + (size_t)M_ * E_;       // Wq,Wk,Wv,Wo bf16 (8 MB)
    unsigned short* bw = Ww + (size_t)4 * E_ * E_;   // bq,bk,bv,bo bf16 (8 KB)
    // ws use: ~48 MB

    cvt_bf16<<<dim3(4100), 256, 0, stream>>>(
        x, Wq, Wk, Wv, Wo, bq, bk, bv, bo, xw, Ww, bw, flag);
    qkv_gemm<<<dim3(768), 256, 0, stream>>>(xw, Ww, bw, qw, kw, vw);
    attn_mfma<<<dim3(NH_ * (T_/128)), 512, 0, stream>>>(qw, kw, vw, rk, rv, aw, flag);
    out_gemm<<<dim3(256), 256, 0, stream>>>(aw, Ww + (size_t)3*E_*E_, bw + 3*E_,
                                            d_out, flag);
}